// Round 1
// baseline (9245.131 us; speedup 1.0000x reference)
//
#include <hip/hip_runtime.h>

#define NN 6000
#define HH 256
#define LL 10
#define KX 30
#define PP 128
#define EE (NN * KX)

// ---------------------------------------------------------------- kNN
__global__ __launch_bounds__(256) void knn_kernel(
    const float* __restrict__ pos, const float* __restrict__ box,
    int* __restrict__ nbr, float* __restrict__ ea, int* __restrict__ counts) {
  __shared__ float sd[NN];
  __shared__ float rv[256];
  __shared__ int ri[256];
  const int a = blockIdx.x, tid = threadIdx.x;
  const float bx = box[0], by = box[1], bz = box[2];
  const float pax = pos[a * 3 + 0], pay = pos[a * 3 + 1], paz = pos[a * 3 + 2];
  for (int j = tid; j < NN; j += 256) {
    float dx = pax - pos[j * 3 + 0]; dx -= rintf(dx / bx) * bx;
    float dy = pay - pos[j * 3 + 1]; dy -= rintf(dy / by) * by;
    float dz = paz - pos[j * 3 + 2]; dz -= rintf(dz / bz) * bz;
    float d2 = dx * dx + dy * dy + dz * dz;
    sd[j] = (j == a) ? 1e9f : d2;
  }
  __syncthreads();
  for (int r = 0; r < KX; ++r) {
    float v = 3e38f; int bi = 0x7fffffff;
    for (int j = tid; j < NN; j += 256) {
      float x = sd[j];
      if (x < v) { v = x; bi = j; }
    }
    rv[tid] = v; ri[tid] = bi;
    __syncthreads();
    for (int s = 128; s > 0; s >>= 1) {
      if (tid < s) {
        float v2 = rv[tid + s]; int i2 = ri[tid + s];
        if (v2 < rv[tid] || (v2 == rv[tid] && i2 < ri[tid])) { rv[tid] = v2; ri[tid] = i2; }
      }
      __syncthreads();
    }
    if (tid == 0) {
      int b = ri[0]; float d2 = rv[0];
      sd[b] = 3e38f;
      nbr[a * KX + r] = b;
      float dx = pax - pos[b * 3 + 0]; dx -= rintf(dx / bx) * bx;
      float dy = pay - pos[b * 3 + 1]; dy -= rintf(dy / by) * by;
      float dz = paz - pos[b * 3 + 2]; dz -= rintf(dz / bz) * bz;
      float4 e4; e4.x = dx; e4.y = dy; e4.z = dz; e4.w = sqrtf(d2);
      *(float4*)&ea[(a * KX + r) * 4] = e4;
      atomicAdd(&counts[b], 1);
    }
    __syncthreads();
  }
}

// ------------------------------------------------- CSR build (deterministic)
__global__ __launch_bounds__(256) void offsets_kernel(
    const int* __restrict__ counts, int* __restrict__ offs, float* __restrict__ invd) {
  __shared__ int ssum[256];
  const int t = threadIdx.x;
  const int lo = t * 24;
  int hi = lo + 24; if (hi > NN) hi = NN;
  int s = 0;
  for (int i = lo; i < hi; ++i) s += counts[i];
  ssum[t] = s;
  __syncthreads();
  for (int o = 1; o < 256; o <<= 1) {
    int v2 = (t >= o) ? ssum[t - o] : 0;
    __syncthreads();
    ssum[t] += v2;
    __syncthreads();
  }
  int run = ssum[t] - s;  // exclusive base
  for (int i = lo; i < hi; ++i) { offs[i] = run; run += counts[i]; }
  if (t == 255) offs[NN] = run;
  for (int i = t; i < NN; i += 256) {
    float c = (float)counts[i];
    invd[i] = 1.0f / fmaxf(c, 1.0f);
  }
}

__global__ __launch_bounds__(256) void scatter_kernel(
    const int* __restrict__ nbr, const int* __restrict__ offs,
    int* __restrict__ cursor, int* __restrict__ elist) {
  const int e = blockIdx.x * 256 + threadIdx.x;
  if (e >= EE) return;
  const int d = nbr[e];
  const int slot = offs[d] + atomicAdd(&cursor[d], 1);
  elist[slot] = e;
}

__global__ __launch_bounds__(256) void sortlists_kernel(
    const int* __restrict__ offs, int* __restrict__ elist) {
  const int b = blockIdx.x * 256 + threadIdx.x;
  if (b >= NN) return;
  const int s = offs[b], t = offs[b + 1];
  for (int i = s + 1; i < t; ++i) {
    int v = elist[i]; int j = i - 1;
    while (j >= s && elist[j] > v) { elist[j + 1] = elist[j]; --j; }
    elist[j + 1] = v;
  }
}

// ---------------------------------------------------------------- encoder
__global__ __launch_bounds__(256) void enc_kernel(
    const float* __restrict__ pos, const float* __restrict__ W,
    const float* __restrict__ b, float* __restrict__ h) {
  const int g = blockIdx.x * 256 + threadIdx.x;  // NN*HH threads
  const int node = g >> 8, c = g & 255;
  h[g] = pos[node * 3 + 0] * W[c] + pos[node * 3 + 1] * W[HH + c] +
         pos[node * 3 + 2] * W[2 * HH + c] + b[c];
}

// --------------------------------------------- shared 16-row register GEMM
#define FMA4(J, F, W) { const float _f = (F); \
  acc[J][0] += _f * (W).x; acc[J][1] += _f * (W).y; \
  acc[J][2] += _f * (W).z; acc[J][3] += _f * (W).w; }

template <int ROWLEN, int KQ>
__device__ __forceinline__ void gemm16(const float* fbase, const float* wcol,
                                       float (&acc)[4][4], const int wv) {
  const float* f0p = fbase + (size_t)wv * ROWLEN;
  const float* f1p = f0p + 4 * ROWLEN;
  const float* f2p = f0p + 8 * ROWLEN;
  const float* f3p = f0p + 12 * ROWLEN;
  const float* wr = wcol;
#pragma unroll 2
  for (int kq = 0; kq < KQ; ++kq) {
    const int kk = kq * 4;
    const float4 w0 = *(const float4*)(wr + 0 * HH);
    const float4 w1 = *(const float4*)(wr + 1 * HH);
    const float4 w2 = *(const float4*)(wr + 2 * HH);
    const float4 w3 = *(const float4*)(wr + 3 * HH);
    const float4 f0 = *(const float4*)(f0p + kk);
    const float4 f1 = *(const float4*)(f1p + kk);
    const float4 f2 = *(const float4*)(f2p + kk);
    const float4 f3 = *(const float4*)(f3p + kk);
    FMA4(0, f0.x, w0) FMA4(0, f0.y, w1) FMA4(0, f0.z, w2) FMA4(0, f0.w, w3)
    FMA4(1, f1.x, w0) FMA4(1, f1.y, w1) FMA4(1, f1.z, w2) FMA4(1, f1.w, w3)
    FMA4(2, f2.x, w0) FMA4(2, f2.y, w1) FMA4(2, f2.z, w2) FMA4(2, f2.w, w3)
    FMA4(3, f3.x, w0) FMA4(3, f3.y, w1) FMA4(3, f3.z, w2) FMA4(3, f3.w, w3)
    wr += 4 * HH;
  }
}

// ---------------------------------------------------------------- msg + agg
__global__ __launch_bounds__(256, 4) void msg_kernel(
    const float* __restrict__ h, float* __restrict__ agg,
    const int* __restrict__ elist, const int* __restrict__ nbr,
    const float* __restrict__ ea,
    const float* __restrict__ mW, const float* __restrict__ mb,
    const float* __restrict__ mg, const float* __restrict__ mbt) {
  __shared__ float feat[16][516];
  __shared__ int sdst[16];
  const int tid = threadIdx.x;
  const int base = blockIdx.x * 16;
  for (int i = 0; i < 16; ++i) {
    const int eid = elist[base + i];
    const int d = nbr[eid];
    const int s = eid / KX;
    feat[i][tid] = h[(size_t)d * HH + tid];
    feat[i][HH + tid] = h[(size_t)s * HH + tid];
    if (tid < 4) feat[i][2 * HH + tid] = ea[eid * 4 + tid];
    if (tid == 0) sdst[i] = d;
  }
  __syncthreads();
  const int lane = tid & 63, wv = tid >> 6;
  const int c4 = lane * 4;
  float acc[4][4] = {};
  gemm16<516, 129>(&feat[0][0], mW + c4, acc, wv);
  const float4 bb = *(const float4*)(mb + c4);
  const float4 gg = *(const float4*)(mg + c4);
  const float4 be = *(const float4*)(mbt + c4);
  int curd = -1;
  float r0 = 0, r1 = 0, r2 = 0, r3 = 0;
#pragma unroll
  for (int j = 0; j < 4; ++j) {
    float v0 = fmaxf(acc[j][0] + bb.x, 0.f);
    float v1 = fmaxf(acc[j][1] + bb.y, 0.f);
    float v2 = fmaxf(acc[j][2] + bb.z, 0.f);
    float v3 = fmaxf(acc[j][3] + bb.w, 0.f);
    float s = v0 + v1 + v2 + v3;
    float s2 = v0 * v0 + v1 * v1 + v2 * v2 + v3 * v3;
#pragma unroll
    for (int o = 1; o < 64; o <<= 1) {
      s += __shfl_xor(s, o, 64);
      s2 += __shfl_xor(s2, o, 64);
    }
    const float mu = s * (1.f / HH);
    const float rs = rsqrtf(s2 * (1.f / HH) - mu * mu + 1e-5f);
    const float m0 = (v0 - mu) * rs * gg.x + be.x;
    const float m1 = (v1 - mu) * rs * gg.y + be.y;
    const float m2 = (v2 - mu) * rs * gg.z + be.z;
    const float m3 = (v3 - mu) * rs * gg.w + be.w;
    const int d = sdst[wv + 4 * j];
    if (d != curd) {
      if (curd >= 0) {
        atomicAdd(&agg[(size_t)curd * HH + c4 + 0], r0);
        atomicAdd(&agg[(size_t)curd * HH + c4 + 1], r1);
        atomicAdd(&agg[(size_t)curd * HH + c4 + 2], r2);
        atomicAdd(&agg[(size_t)curd * HH + c4 + 3], r3);
      }
      curd = d; r0 = m0; r1 = m1; r2 = m2; r3 = m3;
    } else {
      r0 += m0; r1 += m1; r2 += m2; r3 += m3;
    }
  }
  atomicAdd(&agg[(size_t)curd * HH + c4 + 0], r0);
  atomicAdd(&agg[(size_t)curd * HH + c4 + 1], r1);
  atomicAdd(&agg[(size_t)curd * HH + c4 + 2], r2);
  atomicAdd(&agg[(size_t)curd * HH + c4 + 3], r3);
}

// ---------------------------------------------------------------- update
__global__ __launch_bounds__(256, 4) void upd_kernel(
    float* __restrict__ h, const float* __restrict__ agg,
    const float* __restrict__ invd,
    const float* __restrict__ uW, const float* __restrict__ ub,
    const float* __restrict__ ug, const float* __restrict__ ubt) {
  __shared__ float feat[16][512];
  const int tid = threadIdx.x;
  const int base = blockIdx.x * 16;
  for (int i = 0; i < 16; ++i) {
    const int node = base + i;
    feat[i][tid] = h[(size_t)node * HH + tid];
    feat[i][HH + tid] = agg[(size_t)node * HH + tid] * invd[node];
  }
  __syncthreads();
  const int lane = tid & 63, wv = tid >> 6;
  const int c4 = lane * 4;
  float acc[4][4] = {};
  gemm16<512, 128>(&feat[0][0], uW + c4, acc, wv);
  const float4 bb = *(const float4*)(ub + c4);
  const float4 gg = *(const float4*)(ug + c4);
  const float4 be = *(const float4*)(ubt + c4);
#pragma unroll
  for (int j = 0; j < 4; ++j) {
    const int e = wv + 4 * j;
    float v0 = fmaxf(acc[j][0] + bb.x, 0.f);
    float v1 = fmaxf(acc[j][1] + bb.y, 0.f);
    float v2 = fmaxf(acc[j][2] + bb.z, 0.f);
    float v3 = fmaxf(acc[j][3] + bb.w, 0.f);
    float s = v0 + v1 + v2 + v3;
    float s2 = v0 * v0 + v1 * v1 + v2 * v2 + v3 * v3;
#pragma unroll
    for (int o = 1; o < 64; o <<= 1) {
      s += __shfl_xor(s, o, 64);
      s2 += __shfl_xor(s2, o, 64);
    }
    const float mu = s * (1.f / HH);
    const float rs = rsqrtf(s2 * (1.f / HH) - mu * mu + 1e-5f);
    const float4 ho = *(const float4*)(&feat[e][c4]);
    float4 o4;
    o4.x = ho.x + (v0 - mu) * rs * gg.x + be.x;
    o4.y = ho.y + (v1 - mu) * rs * gg.y + be.y;
    o4.z = ho.z + (v2 - mu) * rs * gg.z + be.z;
    o4.w = ho.w + (v3 - mu) * rs * gg.w + be.w;
    *(float4*)(&h[(size_t)(base + e) * HH + c4]) = o4;
  }
}

// ---------------------------------------------------------------- projection
__global__ __launch_bounds__(256, 4) void proj_kernel(
    const float* __restrict__ h,
    const float* __restrict__ W1, const float* __restrict__ b1,
    const float* __restrict__ W2, const float* __restrict__ b2,
    float* __restrict__ out) {
  __shared__ float sh[16][256];
  __shared__ float st[16][256];
  const int tid = threadIdx.x, base = blockIdx.x * 16;
  for (int i = 0; i < 16; ++i) sh[i][tid] = h[(size_t)(base + i) * HH + tid];
  __syncthreads();
  const int lane = tid & 63, wv = tid >> 6;
  const int c4 = lane * 4;
  float acc[4][4] = {};
  gemm16<256, 64>(&sh[0][0], W1 + c4, acc, wv);
  const float4 bb = *(const float4*)(b1 + c4);
#pragma unroll
  for (int j = 0; j < 4; ++j) {
    const int e = wv + 4 * j;
    st[e][c4 + 0] = fmaxf(acc[j][0] + bb.x, 0.f);
    st[e][c4 + 1] = fmaxf(acc[j][1] + bb.y, 0.f);
    st[e][c4 + 2] = fmaxf(acc[j][2] + bb.z, 0.f);
    st[e][c4 + 3] = fmaxf(acc[j][3] + bb.w, 0.f);
  }
  __syncthreads();
  const int c2 = lane * 2;
  float a0[4] = {}, a1[4] = {};
  const float* w2p = W2 + c2;
#pragma unroll 2
  for (int kk = 0; kk < 256; ++kk) {
    const float2 w = *(const float2*)(w2p + (size_t)kk * PP);
    const float g0 = st[wv + 0][kk];
    const float g1 = st[wv + 4][kk];
    const float g2 = st[wv + 8][kk];
    const float g3 = st[wv + 12][kk];
    a0[0] += g0 * w.x; a1[0] += g0 * w.y;
    a0[1] += g1 * w.x; a1[1] += g1 * w.y;
    a0[2] += g2 * w.x; a1[2] += g2 * w.y;
    a0[3] += g3 * w.x; a1[3] += g3 * w.y;
  }
  const float2 b2v = *(const float2*)(b2 + c2);
#pragma unroll
  for (int j = 0; j < 4; ++j) {
    const int node = base + wv + 4 * j;
    out[(size_t)node * PP + c2 + 0] = a0[j] + b2v.x;
    out[(size_t)node * PP + c2 + 1] = a1[j] + b2v.y;
  }
}

// ---------------------------------------------------------------- launcher
extern "C" void kernel_launch(void* const* d_in, const int* in_sizes, int n_in,
                              void* d_out, int out_size, void* d_ws, size_t ws_size,
                              hipStream_t stream) {
  const float* pos   = (const float*)d_in[0];
  const float* box   = (const float*)d_in[1];
  const float* encW  = (const float*)d_in[2];
  const float* encB  = (const float*)d_in[3];
  const float* msgW  = (const float*)d_in[4];
  const float* msgB  = (const float*)d_in[5];
  const float* msgG  = (const float*)d_in[6];
  const float* msgBt = (const float*)d_in[7];
  const float* updW  = (const float*)d_in[8];
  const float* updB  = (const float*)d_in[9];
  const float* updG  = (const float*)d_in[10];
  const float* updBt = (const float*)d_in[11];
  const float* pW1   = (const float*)d_in[12];
  const float* pb1   = (const float*)d_in[13];
  const float* pW2   = (const float*)d_in[14];
  const float* pb2   = (const float*)d_in[15];
  float* out = (float*)d_out;

  char* w = (char*)d_ws;
  auto alloc = [&](size_t bytes) {
    char* p = w;
    w += (bytes + 255) & ~(size_t)255;
    return p;
  };
  int*   nbr    = (int*)alloc((size_t)EE * 4);
  float* ea     = (float*)alloc((size_t)EE * 16);
  int*   counts = (int*)alloc((size_t)NN * 4);
  int*   offs   = (int*)alloc((size_t)(NN + 1) * 4);
  int*   cursor = (int*)alloc((size_t)NN * 4);
  int*   elist  = (int*)alloc((size_t)EE * 4);
  float* invd   = (float*)alloc((size_t)NN * 4);
  float* hbuf   = (float*)alloc((size_t)NN * HH * 4);
  float* agg    = (float*)alloc((size_t)NN * HH * 4);

  hipMemsetAsync(counts, 0, (size_t)NN * 4, stream);
  hipMemsetAsync(cursor, 0, (size_t)NN * 4, stream);

  knn_kernel<<<NN, 256, 0, stream>>>(pos, box, nbr, ea, counts);
  offsets_kernel<<<1, 256, 0, stream>>>(counts, offs, invd);
  scatter_kernel<<<(EE + 255) / 256, 256, 0, stream>>>(nbr, offs, cursor, elist);
  sortlists_kernel<<<(NN + 255) / 256, 256, 0, stream>>>(offs, elist);
  enc_kernel<<<NN, 256, 0, stream>>>(pos, encW, encB, hbuf);

  for (int l = 0; l < LL; ++l) {
    hipMemsetAsync(agg, 0, (size_t)NN * HH * 4, stream);
    msg_kernel<<<EE / 16, 256, 0, stream>>>(
        hbuf, agg, elist, nbr, ea,
        msgW + (size_t)l * 516 * HH, msgB + (size_t)l * HH,
        msgG + (size_t)l * HH, msgBt + (size_t)l * HH);
    upd_kernel<<<NN / 16, 256, 0, stream>>>(
        hbuf, agg, invd,
        updW + (size_t)l * 512 * HH, updB + (size_t)l * HH,
        updG + (size_t)l * HH, updBt + (size_t)l * HH);
  }
  proj_kernel<<<NN / 16, 256, 0, stream>>>(hbuf, pW1, pb1, pW2, pb2, out);
}

// Round 5
// 2432.823 us; speedup vs baseline: 3.8002x; 3.8002x over previous
//
#include <hip/hip_runtime.h>

#define NN 6000
#define HH 256
#define LL 10
#define KX 30
#define PP 128
#define EE (NN * KX)
#define EB 48        // edges per msg block
#define RPAD 552     // feat row stride (ushorts): 1104B = 276 words == 20 mod 32 -> 2-way
#define KPADM 544    // msg BT row length (516 padded to 17*32)
#define KPADU 512    // upd BT row length
#define UB 16        // nodes per upd block
#define RPADU 520    // 1040B = 260 words == 4 mod 32 -> 2-way

typedef __attribute__((ext_vector_type(8))) short short8;
typedef __attribute__((ext_vector_type(4))) float f32x4;

__device__ __forceinline__ unsigned short f2bf(float x) {
  union { float f; unsigned u; } v; v.f = x;
  return (unsigned short)((v.u + 0x7fffu + ((v.u >> 16) & 1u)) >> 16);
}

// ---------------------------------------------------------------- kNN
__global__ __launch_bounds__(256) void knn_kernel(
    const float* __restrict__ pos, const float* __restrict__ box,
    int* __restrict__ nbr, float* __restrict__ ea, int* __restrict__ counts) {
  __shared__ float sd[NN];
  __shared__ float rv[256];
  __shared__ int ri[256];
  const int a = blockIdx.x, tid = threadIdx.x;
  const float bx = box[0], by = box[1], bz = box[2];
  const float pax = pos[a * 3 + 0], pay = pos[a * 3 + 1], paz = pos[a * 3 + 2];
  for (int j = tid; j < NN; j += 256) {
    float dx = pax - pos[j * 3 + 0]; dx -= rintf(dx / bx) * bx;
    float dy = pay - pos[j * 3 + 1]; dy -= rintf(dy / by) * by;
    float dz = paz - pos[j * 3 + 2]; dz -= rintf(dz / bz) * bz;
    float d2 = dx * dx + dy * dy + dz * dz;
    sd[j] = (j == a) ? 1e9f : d2;
  }
  __syncthreads();
  for (int r = 0; r < KX; ++r) {
    float v = 3e38f; int bi = 0x7fffffff;
    for (int j = tid; j < NN; j += 256) {
      float x = sd[j];
      if (x < v) { v = x; bi = j; }
    }
    rv[tid] = v; ri[tid] = bi;
    __syncthreads();
    for (int s = 128; s > 0; s >>= 1) {
      if (tid < s) {
        float v2 = rv[tid + s]; int i2 = ri[tid + s];
        if (v2 < rv[tid] || (v2 == rv[tid] && i2 < ri[tid])) { rv[tid] = v2; ri[tid] = i2; }
      }
      __syncthreads();
    }
    if (tid == 0) {
      int b = ri[0]; float d2 = rv[0];
      sd[b] = 3e38f;
      nbr[a * KX + r] = b;
      float dx = pax - pos[b * 3 + 0]; dx -= rintf(dx / bx) * bx;
      float dy = pay - pos[b * 3 + 1]; dy -= rintf(dy / by) * by;
      float dz = paz - pos[b * 3 + 2]; dz -= rintf(dz / bz) * bz;
      float4 e4; e4.x = dx; e4.y = dy; e4.z = dz; e4.w = sqrtf(d2);
      *(float4*)&ea[(a * KX + r) * 4] = e4;
      atomicAdd(&counts[b], 1);
    }
    __syncthreads();
  }
}

// ------------------------------------------------- CSR build (deterministic)
__global__ __launch_bounds__(256) void offsets_kernel(
    const int* __restrict__ counts, int* __restrict__ offs, float* __restrict__ invd) {
  __shared__ int ssum[256];
  const int t = threadIdx.x;
  const int lo = t * 24;
  int hi = lo + 24; if (hi > NN) hi = NN;
  int s = 0;
  for (int i = lo; i < hi; ++i) s += counts[i];
  ssum[t] = s;
  __syncthreads();
  for (int o = 1; o < 256; o <<= 1) {
    int v2 = (t >= o) ? ssum[t - o] : 0;
    __syncthreads();
    ssum[t] += v2;
    __syncthreads();
  }
  int run = ssum[t] - s;
  for (int i = lo; i < hi; ++i) { offs[i] = run; run += counts[i]; }
  if (t == 255) offs[NN] = run;
  for (int i = t; i < NN; i += 256) {
    float c = (float)counts[i];
    invd[i] = 1.0f / fmaxf(c, 1.0f);
  }
}

__global__ __launch_bounds__(256) void scatter_kernel(
    const int* __restrict__ nbr, const int* __restrict__ offs,
    int* __restrict__ cursor, int* __restrict__ elist) {
  const int e = blockIdx.x * 256 + threadIdx.x;
  if (e >= EE) return;
  const int d = nbr[e];
  const int slot = offs[d] + atomicAdd(&cursor[d], 1);
  elist[slot] = e;
}

__global__ __launch_bounds__(256) void sortlists_kernel(
    const int* __restrict__ offs, int* __restrict__ elist) {
  const int b = blockIdx.x * 256 + threadIdx.x;
  if (b >= NN) return;
  const int s = offs[b], t = offs[b + 1];
  for (int i = s + 1; i < t; ++i) {
    int v = elist[i]; int j = i - 1;
    while (j >= s && elist[j] > v) { elist[j + 1] = elist[j]; --j; }
    elist[j + 1] = v;
  }
}

// --------------------------------------- weight transpose + bf16 conversion
// W: [LL][K][256] f32  ->  BT: [LL][256][Kpad] bf16 (zeros for k >= K)
__global__ __launch_bounds__(256) void wcvt_kernel(
    const float* __restrict__ W, unsigned short* __restrict__ BT,
    int K, int Kpad) {
  __shared__ unsigned short t[64][65];
  const int l = blockIdx.x, k0 = blockIdx.y * 64, n0 = blockIdx.z * 64;
  const int tid = threadIdx.x, tc = tid & 63, tr = tid >> 6;
  const float* Wl = W + (size_t)l * K * 256;
  unsigned short* BTl = BT + (size_t)l * 256 * Kpad;
  for (int r = tr; r < 64; r += 4) {
    int k = k0 + r;
    float v = (k < K) ? Wl[(size_t)k * 256 + n0 + tc] : 0.f;
    t[r][tc] = f2bf(v);
  }
  __syncthreads();
  for (int r = tr; r < 64; r += 4) {
    int n = n0 + r, k = k0 + tc;
    if (k < Kpad) BTl[(size_t)n * Kpad + k] = t[tc][r];
  }
}

// ---------------------------------------------------------------- encoder
__global__ __launch_bounds__(256) void enc_kernel(
    const float* __restrict__ pos, const float* __restrict__ W,
    const float* __restrict__ b, float* __restrict__ h,
    unsigned short* __restrict__ hb) {
  const int gidx = blockIdx.x * 256 + threadIdx.x;
  const int node = gidx >> 8, c = gidx & 255;
  float v = pos[node * 3 + 0] * W[c] + pos[node * 3 + 1] * W[HH + c] +
            pos[node * 3 + 2] * W[2 * HH + c] + b[c];
  h[gidx] = v;
  hb[gidx] = f2bf(v);
}

// ------------------------------------------------------- msg (MFMA) + agg
__global__ __launch_bounds__(256, 2) void msg_mfma(
    const unsigned short* __restrict__ hb, float* __restrict__ agg,
    const int* __restrict__ elist, const int* __restrict__ nbr,
    const float* __restrict__ ea, const unsigned short* __restrict__ BT,
    const float* __restrict__ mb, const float* __restrict__ mg,
    const float* __restrict__ mbt) {
  __shared__ __align__(16) char smem[EB * RPAD * 2];  // feat (bf16) / mbuf (f32) overlay
  __shared__ int sdst[EB], ssrc[EB], seid[EB];
  __shared__ float psum[EB][4], psum2[EB][4], smu[EB], srs[EB];
  unsigned short* feat = (unsigned short*)smem;
  float* mbuf = (float*)smem;
  const int tid = threadIdx.x;
  const int base = blockIdx.x * EB;
  if (tid < EB) {
    int eid = elist[base + tid];
    seid[tid] = eid; sdst[tid] = nbr[eid]; ssrc[tid] = eid / KX;
  }
  __syncthreads();
  {
    const int lane = tid & 63, grp = tid >> 6;
    for (int it = 0; it < 24; ++it) {
      int hr = it * 4 + grp;
      int e = hr >> 1, half = hr & 1;
      int node = half ? ssrc[e] : sdst[e];
      ushort4 v = *(const ushort4*)(hb + (size_t)node * HH + (tid & 63) * 4);
      *(ushort4*)&feat[e * RPAD + half * HH + lane * 4] = v;
    }
  }
  for (int s = tid; s < EB * 4; s += 256) {
    int e = s >> 2, j = s & 3;
    feat[e * RPAD + 512 + j] = f2bf(ea[(size_t)seid[e] * 4 + j]);
  }
  for (int s = tid; s < EB * 28; s += 256) {
    int e = s / 28, k = s - e * 28;
    feat[e * RPAD + 516 + k] = 0;
  }
  __syncthreads();
  const int lane = tid & 63, wv = tid >> 6;
  const int m = lane & 15, g = lane >> 4;
  const int n0 = wv * 64;
  f32x4 acc[3][4] = {};
  {
    const unsigned short* a0p = feat + m * RPAD + g * 8;
    const unsigned short* a1p = a0p + 16 * RPAD;
    const unsigned short* a2p = a0p + 32 * RPAD;
    const unsigned short* bp0 = BT + (size_t)(n0 + m) * KPADM + g * 8;
    const unsigned short* bp1 = bp0 + 16 * KPADM;
    const unsigned short* bp2 = bp0 + 32 * KPADM;
    const unsigned short* bp3 = bp0 + 48 * KPADM;
    for (int ks = 0; ks < 17; ++ks) {
      const int ko = ks * 32;
      short8 b0 = *(const short8*)(bp0 + ko);
      short8 b1 = *(const short8*)(bp1 + ko);
      short8 b2 = *(const short8*)(bp2 + ko);
      short8 b3 = *(const short8*)(bp3 + ko);
      short8 a0 = *(const short8*)(a0p + ko);
      short8 a1 = *(const short8*)(a1p + ko);
      short8 a2 = *(const short8*)(a2p + ko);
      acc[0][0] = __builtin_amdgcn_mfma_f32_16x16x32_bf16(a0, b0, acc[0][0], 0, 0, 0);
      acc[0][1] = __builtin_amdgcn_mfma_f32_16x16x32_bf16(a0, b1, acc[0][1], 0, 0, 0);
      acc[0][2] = __builtin_amdgcn_mfma_f32_16x16x32_bf16(a0, b2, acc[0][2], 0, 0, 0);
      acc[0][3] = __builtin_amdgcn_mfma_f32_16x16x32_bf16(a0, b3, acc[0][3], 0, 0, 0);
      acc[1][0] = __builtin_amdgcn_mfma_f32_16x16x32_bf16(a1, b0, acc[1][0], 0, 0, 0);
      acc[1][1] = __builtin_amdgcn_mfma_f32_16x16x32_bf16(a1, b1, acc[1][1], 0, 0, 0);
      acc[1][2] = __builtin_amdgcn_mfma_f32_16x16x32_bf16(a1, b2, acc[1][2], 0, 0, 0);
      acc[1][3] = __builtin_amdgcn_mfma_f32_16x16x32_bf16(a1, b3, acc[1][3], 0, 0, 0);
      acc[2][0] = __builtin_amdgcn_mfma_f32_16x16x32_bf16(a2, b0, acc[2][0], 0, 0, 0);
      acc[2][1] = __builtin_amdgcn_mfma_f32_16x16x32_bf16(a2, b1, acc[2][1], 0, 0, 0);
      acc[2][2] = __builtin_amdgcn_mfma_f32_16x16x32_bf16(a2, b2, acc[2][2], 0, 0, 0);
      acc[2][3] = __builtin_amdgcn_mfma_f32_16x16x32_bf16(a2, b3, acc[2][3], 0, 0, 0);
    }
  }
  float bb[4], gg4[4], be4[4];
#pragma unroll
  for (int nt = 0; nt < 4; ++nt) {
    int c = n0 + nt * 16 + m;
    bb[nt] = mb[c]; gg4[nt] = mg[c]; be4[nt] = mbt[c];
  }
#pragma unroll
  for (int rt = 0; rt < 3; ++rt)
#pragma unroll
    for (int i = 0; i < 4; ++i) {
      float s = 0.f, s2 = 0.f;
#pragma unroll
      for (int nt = 0; nt < 4; ++nt) {
        float v = fmaxf(acc[rt][nt][i] + bb[nt], 0.f);
        acc[rt][nt][i] = v; s += v; s2 += v * v;
      }
#pragma unroll
      for (int o = 1; o < 16; o <<= 1) {
        s += __shfl_xor(s, o, 64);
        s2 += __shfl_xor(s2, o, 64);
      }
      if (m == 0) { int e = rt * 16 + g * 4 + i; psum[e][wv] = s; psum2[e][wv] = s2; }
    }
  __syncthreads();
  if (tid < EB) {
    float s = psum[tid][0] + psum[tid][1] + psum[tid][2] + psum[tid][3];
    float s2 = psum2[tid][0] + psum2[tid][1] + psum2[tid][2] + psum2[tid][3];
    float mu = s * (1.f / HH);
    smu[tid] = mu;
    srs[tid] = rsqrtf(s2 * (1.f / HH) - mu * mu + 1e-5f);
  }
  __syncthreads();
  // write LN'd messages into mbuf (feat overlay; feat dead since MFMA loop)
#pragma unroll
  for (int rt = 0; rt < 3; ++rt)
#pragma unroll
    for (int i = 0; i < 4; ++i) {
      int e = rt * 16 + g * 4 + i;
      float mu = smu[e], rs = srs[e];
#pragma unroll
      for (int nt = 0; nt < 4; ++nt)
        mbuf[e * 260 + n0 + nt * 16 + m] = (acc[rt][nt][i] - mu) * rs * gg4[nt] + be4[nt];
    }
  __syncthreads();
  // dst-sorted run merge: one column per thread, ~2-4 atomics per column
  {
    float r = 0.f; int curd = sdst[0];
    for (int e = 0; e < EB; ++e) {
      int d = sdst[e];
      if (d != curd) {
        atomicAdd(&agg[(size_t)curd * HH + tid], r);
        r = 0.f; curd = d;
      }
      r += mbuf[e * 260 + tid];
    }
    atomicAdd(&agg[(size_t)curd * HH + tid], r);
  }
}

// ---------------------------------------------------------------- upd (MFMA)
__global__ __launch_bounds__(256, 2) void upd_mfma(
    float* __restrict__ h, unsigned short* __restrict__ hb,
    const float* __restrict__ agg, const float* __restrict__ invd,
    const unsigned short* __restrict__ BT, const float* __restrict__ ub,
    const float* __restrict__ ug, const float* __restrict__ ubt) {
  __shared__ __align__(16) unsigned short feat[UB * RPADU];
  __shared__ float psum[UB][4], psum2[UB][4], smu[UB], srs[UB], sinv[UB];
  const int tid = threadIdx.x;
  const int base = blockIdx.x * UB;
  if (tid < UB) sinv[tid] = invd[base + tid];
  __syncthreads();
  {
    const int lane = tid & 63, grp = tid >> 6;
    for (int it = 0; it < 8; ++it) {
      int hr = it * 4 + grp;
      int e = hr >> 1, half = hr & 1;
      int node = base + e;
      ushort4 o;
      if (half == 0) {
        o = *(const ushort4*)(hb + (size_t)node * HH + lane * 4);
      } else {
        float4 a4 = *(const float4*)(agg + (size_t)node * HH + lane * 4);
        float iv = sinv[e];
        o.x = f2bf(a4.x * iv); o.y = f2bf(a4.y * iv);
        o.z = f2bf(a4.z * iv); o.w = f2bf(a4.w * iv);
      }
      *(ushort4*)&feat[e * RPADU + half * HH + lane * 4] = o;
    }
  }
  __syncthreads();
  const int lane = tid & 63, wv = tid >> 6;
  const int m = lane & 15, g = lane >> 4;
  const int n0 = wv * 64;
  f32x4 acc[4] = {};
  {
    const unsigned short* ap = feat + m * RPADU + g * 8;
    const unsigned short* bp0 = BT + (size_t)(n0 + m) * KPADU + g * 8;
    const unsigned short* bp1 = bp0 + 16 * KPADU;
    const unsigned short* bp2 = bp0 + 32 * KPADU;
    const unsigned short* bp3 = bp0 + 48 * KPADU;
    for (int ks = 0; ks < 16; ++ks) {
      const int ko = ks * 32;
      short8 a = *(const short8*)(ap + ko);
      acc[0] = __builtin_amdgcn_mfma_f32_16x16x32_bf16(a, *(const short8*)(bp0 + ko), acc[0], 0, 0, 0);
      acc[1] = __builtin_amdgcn_mfma_f32_16x16x32_bf16(a, *(const short8*)(bp1 + ko), acc[1], 0, 0, 0);
      acc[2] = __builtin_amdgcn_mfma_f32_16x16x32_bf16(a, *(const short8*)(bp2 + ko), acc[2], 0, 0, 0);
      acc[3] = __builtin_amdgcn_mfma_f32_16x16x32_bf16(a, *(const short8*)(bp3 + ko), acc[3], 0, 0, 0);
    }
  }
  float bb[4], gg4[4], be4[4];
#pragma unroll
  for (int nt = 0; nt < 4; ++nt) {
    int c = n0 + nt * 16 + m;
    bb[nt] = ub[c]; gg4[nt] = ug[c]; be4[nt] = ubt[c];
  }
#pragma unroll
  for (int i = 0; i < 4; ++i) {
    float s = 0.f, s2 = 0.f;
#pragma unroll
    for (int nt = 0; nt < 4; ++nt) {
      float v = fmaxf(acc[nt][i] + bb[nt], 0.f);
      acc[nt][i] = v; s += v; s2 += v * v;
    }
#pragma unroll
    for (int o = 1; o < 16; o <<= 1) {
      s += __shfl_xor(s, o, 64);
      s2 += __shfl_xor(s2, o, 64);
    }
    if (m == 0) { int e = g * 4 + i; psum[e][wv] = s; psum2[e][wv] = s2; }
  }
  __syncthreads();
  if (tid < UB) {
    float s = psum[tid][0] + psum[tid][1] + psum[tid][2] + psum[tid][3];
    float s2 = psum2[tid][0] + psum2[tid][1] + psum2[tid][2] + psum2[tid][3];
    float mu = s * (1.f / HH);
    smu[tid] = mu;
    srs[tid] = rsqrtf(s2 * (1.f / HH) - mu * mu + 1e-5f);
  }
  __syncthreads();
#pragma unroll
  for (int i = 0; i < 4; ++i) {
    int e = g * 4 + i;
    int node = base + e;
    float mu = smu[e], rs = srs[e];
#pragma unroll
    for (int nt = 0; nt < 4; ++nt) {
      int c = n0 + nt * 16 + m;
      float u = (acc[nt][i] - mu) * rs * gg4[nt] + be4[nt];
      float hn = h[(size_t)node * HH + c] + u;
      h[(size_t)node * HH + c] = hn;
      hb[(size_t)node * HH + c] = f2bf(hn);
    }
  }
}

// --------------------------------------------- fp32 register GEMM (proj only)
#define FMA4(J, F, W) { const float _f = (F); \
  acc[J][0] += _f * (W).x; acc[J][1] += _f * (W).y; \
  acc[J][2] += _f * (W).z; acc[J][3] += _f * (W).w; }

template <int ROWLEN, int KQ>
__device__ __forceinline__ void gemm16(const float* fbase, const float* wcol,
                                       float (&acc)[4][4], const int wv) {
  const float* f0p = fbase + (size_t)wv * ROWLEN;
  const float* f1p = f0p + 4 * ROWLEN;
  const float* f2p = f0p + 8 * ROWLEN;
  const float* f3p = f0p + 12 * ROWLEN;
  const float* wr = wcol;
#pragma unroll 2
  for (int kq = 0; kq < KQ; ++kq) {
    const int kk = kq * 4;
    const float4 w0 = *(const float4*)(wr + 0 * HH);
    const float4 w1 = *(const float4*)(wr + 1 * HH);
    const float4 w2 = *(const float4*)(wr + 2 * HH);
    const float4 w3 = *(const float4*)(wr + 3 * HH);
    const float4 f0 = *(const float4*)(f0p + kk);
    const float4 f1 = *(const float4*)(f1p + kk);
    const float4 f2 = *(const float4*)(f2p + kk);
    const float4 f3 = *(const float4*)(f3p + kk);
    FMA4(0, f0.x, w0) FMA4(0, f0.y, w1) FMA4(0, f0.z, w2) FMA4(0, f0.w, w3)
    FMA4(1, f1.x, w0) FMA4(1, f1.y, w1) FMA4(1, f1.z, w2) FMA4(1, f1.w, w3)
    FMA4(2, f2.x, w0) FMA4(2, f2.y, w1) FMA4(2, f2.z, w2) FMA4(2, f2.w, w3)
    FMA4(3, f3.x, w0) FMA4(3, f3.y, w1) FMA4(3, f3.z, w2) FMA4(3, f3.w, w3)
    wr += 4 * HH;
  }
}

// ---------------------------------------------------------------- projection
__global__ __launch_bounds__(256, 4) void proj_kernel(
    const float* __restrict__ h,
    const float* __restrict__ W1, const float* __restrict__ b1,
    const float* __restrict__ W2, const float* __restrict__ b2,
    float* __restrict__ out) {
  __shared__ float sh[16][256];
  __shared__ float st[16][256];
  const int tid = threadIdx.x, base = blockIdx.x * 16;
  for (int i = 0; i < 16; ++i) sh[i][tid] = h[(size_t)(base + i) * HH + tid];
  __syncthreads();
  const int lane = tid & 63, wv = tid >> 6;
  const int c4 = lane * 4;
  float acc[4][4] = {};
  gemm16<256, 64>(&sh[0][0], W1 + c4, acc, wv);
  const float4 bb = *(const float4*)(b1 + c4);
#pragma unroll
  for (int j = 0; j < 4; ++j) {
    const int e = wv + 4 * j;
    st[e][c4 + 0] = fmaxf(acc[j][0] + bb.x, 0.f);
    st[e][c4 + 1] = fmaxf(acc[j][1] + bb.y, 0.f);
    st[e][c4 + 2] = fmaxf(acc[j][2] + bb.z, 0.f);
    st[e][c4 + 3] = fmaxf(acc[j][3] + bb.w, 0.f);
  }
  __syncthreads();
  const int c2 = lane * 2;
  float a0[4] = {}, a1[4] = {};
  const float* w2p = W2 + c2;
#pragma unroll 2
  for (int kk = 0; kk < 256; ++kk) {
    const float2 w = *(const float2*)(w2p + (size_t)kk * PP);
    const float g0 = st[wv + 0][kk];
    const float g1 = st[wv + 4][kk];
    const float g2 = st[wv + 8][kk];
    const float g3 = st[wv + 12][kk];
    a0[0] += g0 * w.x; a1[0] += g0 * w.y;
    a0[1] += g1 * w.x; a1[1] += g1 * w.y;
    a0[2] += g2 * w.x; a1[2] += g2 * w.y;
    a0[3] += g3 * w.x; a1[3] += g3 * w.y;
  }
  const float2 b2v = *(const float2*)(b2 + c2);
#pragma unroll
  for (int j = 0; j < 4; ++j) {
    const int node = base + wv + 4 * j;
    out[(size_t)node * PP + c2 + 0] = a0[j] + b2v.x;
    out[(size_t)node * PP + c2 + 1] = a1[j] + b2v.y;
  }
}

// ---------------------------------------------------------------- launcher
extern "C" void kernel_launch(void* const* d_in, const int* in_sizes, int n_in,
                              void* d_out, int out_size, void* d_ws, size_t ws_size,
                              hipStream_t stream) {
  const float* pos   = (const float*)d_in[0];
  const float* box   = (const float*)d_in[1];
  const float* encW  = (const float*)d_in[2];
  const float* encB  = (const float*)d_in[3];
  const float* msgW  = (const float*)d_in[4];
  const float* msgB  = (const float*)d_in[5];
  const float* msgG  = (const float*)d_in[6];
  const float* msgBt = (const float*)d_in[7];
  const float* updW  = (const float*)d_in[8];
  const float* updB  = (const float*)d_in[9];
  const float* updG  = (const float*)d_in[10];
  const float* updBt = (const float*)d_in[11];
  const float* pW1   = (const float*)d_in[12];
  const float* pb1   = (const float*)d_in[13];
  const float* pW2   = (const float*)d_in[14];
  const float* pb2   = (const float*)d_in[15];
  float* out = (float*)d_out;

  char* w = (char*)d_ws;
  auto alloc = [&](size_t bytes) {
    char* p = w;
    w += (bytes + 255) & ~(size_t)255;
    return p;
  };
  int*   nbr    = (int*)alloc((size_t)EE * 4);
  float* ea     = (float*)alloc((size_t)EE * 16);
  int*   counts = (int*)alloc((size_t)NN * 4);
  int*   offs   = (int*)alloc((size_t)(NN + 1) * 4);
  int*   cursor = (int*)alloc((size_t)NN * 4);
  int*   elist  = (int*)alloc((size_t)EE * 4);
  float* invd   = (float*)alloc((size_t)NN * 4);
  float* hbuf   = (float*)alloc((size_t)NN * HH * 4);
  float* agg    = (float*)alloc((size_t)NN * HH * 4);
  unsigned short* hb  = (unsigned short*)alloc((size_t)NN * HH * 2);
  unsigned short* mBT = (unsigned short*)alloc((size_t)LL * 256 * KPADM * 2);
  unsigned short* uBT = (unsigned short*)alloc((size_t)LL * 256 * KPADU * 2);

  hipMemsetAsync(counts, 0, (size_t)NN * 4, stream);
  hipMemsetAsync(cursor, 0, (size_t)NN * 4, stream);

  wcvt_kernel<<<dim3(LL, 9, 4), 256, 0, stream>>>(msgW, mBT, 516, KPADM);
  wcvt_kernel<<<dim3(LL, 8, 4), 256, 0, stream>>>(updW, uBT, 512, KPADU);

  knn_kernel<<<NN, 256, 0, stream>>>(pos, box, nbr, ea, counts);
  offsets_kernel<<<1, 256, 0, stream>>>(counts, offs, invd);
  scatter_kernel<<<(EE + 255) / 256, 256, 0, stream>>>(nbr, offs, cursor, elist);
  sortlists_kernel<<<(NN + 255) / 256, 256, 0, stream>>>(offs, elist);
  enc_kernel<<<NN, 256, 0, stream>>>(pos, encW, encB, hbuf, hb);

  for (int l = 0; l < LL; ++l) {
    hipMemsetAsync(agg, 0, (size_t)NN * HH * 4, stream);
    msg_mfma<<<EE / EB, 256, 0, stream>>>(
        hb, agg, elist, nbr, ea,
        mBT + (size_t)l * 256 * KPADM,
        msgB + (size_t)l * HH, msgG + (size_t)l * HH, msgBt + (size_t)l * HH);
    upd_mfma<<<NN / UB, 256, 0, stream>>>(
        hbuf, hb, agg, invd,
        uBT + (size_t)l * 256 * KPADU,
        updB + (size_t)l * HH, updG + (size_t)l * HH, updBt + (size_t)l * HH);
  }
  proj_kernel<<<NN / 16, 256, 0, stream>>>(hbuf, pW1, pb1, pW2, pb2, out);
}

// Round 6
// 2338.859 us; speedup vs baseline: 3.9528x; 1.0402x over previous
//
#include <hip/hip_runtime.h>

#define NN 6000
#define HH 256
#define LL 10
#define KX 30
#define PP 128
#define EE (NN * KX)
#define EB 48        // edges per msg block
#define RPAD 552     // feat row stride (ushorts): 1104B = 276 words == 20 mod 32 -> 2-way
#define KPADM 544    // msg BT row length (516 padded to 17*32)
#define KPADU 512    // upd BT row length
#define UB 16        // nodes per upd block
#define RPADU 520    // 1040B = 260 words == 4 mod 32 -> 2-way

typedef __attribute__((ext_vector_type(8))) short short8;
typedef __attribute__((ext_vector_type(4))) float f32x4;

__device__ __forceinline__ unsigned short f2bf(float x) {
  union { float f; unsigned u; } v; v.f = x;
  return (unsigned short)((v.u + 0x7fffu + ((v.u >> 16) & 1u)) >> 16);
}

// ---------------------------------------------------------------- kNN
// register-resident distances; lazy local-argmin rescan (only the winner's
// owner thread rescans its 24 registers each round). 2 barriers/round.
__global__ __launch_bounds__(256) void knn_kernel(
    const float* __restrict__ pos, const float* __restrict__ box,
    int* __restrict__ nbr, float* __restrict__ ea, int* __restrict__ counts) {
  __shared__ float wvv[4];
  __shared__ int wvi[4];
  const int a = blockIdx.x, tid = threadIdx.x;
  const int lane = tid & 63, wv = tid >> 6;
  const float bx = box[0], by = box[1], bz = box[2];
  const float pax = pos[a * 3 + 0], pay = pos[a * 3 + 1], paz = pos[a * 3 + 2];
  float v[24];
#pragma unroll
  for (int q = 0; q < 24; ++q) {
    int j = tid + (q << 8);
    float d2 = 3e38f;
    if (j < NN && j != a) {
      float dx = pax - pos[j * 3 + 0]; dx -= rintf(dx / bx) * bx;
      float dy = pay - pos[j * 3 + 1]; dy -= rintf(dy / by) * by;
      float dz = paz - pos[j * 3 + 2]; dz -= rintf(dz / bz) * bz;
      d2 = dx * dx + dy * dy + dz * dz;
    }
    v[q] = d2;
  }
  float lmin = v[0]; int larg = tid;
#pragma unroll
  for (int q = 1; q < 24; ++q) {
    int j = tid + (q << 8);
    if (v[q] < lmin) { lmin = v[q]; larg = j; }
  }
  for (int r = 0; r < KX; ++r) {
    float m = lmin; int ar = larg;
#pragma unroll
    for (int o = 1; o < 64; o <<= 1) {
      float m2 = __shfl_xor(m, o, 64);
      int a2 = __shfl_xor(ar, o, 64);
      if (m2 < m || (m2 == m && a2 < ar)) { m = m2; ar = a2; }
    }
    if (lane == 0) { wvv[wv] = m; wvi[wv] = ar; }
    __syncthreads();
    float gm = wvv[0]; int ga = wvi[0];
#pragma unroll
    for (int w = 1; w < 4; ++w) {
      float m2 = wvv[w]; int a2 = wvi[w];
      if (m2 < gm || (m2 == gm && a2 < ga)) { gm = m2; ga = a2; }
    }
    if (tid == 0) {
      int b = ga;
      nbr[a * KX + r] = b;
      float dx = pax - pos[b * 3 + 0]; dx -= rintf(dx / bx) * bx;
      float dy = pay - pos[b * 3 + 1]; dy -= rintf(dy / by) * by;
      float dz = paz - pos[b * 3 + 2]; dz -= rintf(dz / bz) * bz;
      float4 e4; e4.x = dx; e4.y = dy; e4.z = dz; e4.w = sqrtf(gm);
      *(float4*)&ea[(a * KX + r) * 4] = e4;
      atomicAdd(&counts[b], 1);
    }
    if ((ga & 255) == tid) {
      const int qq = ga >> 8;
#pragma unroll
      for (int q = 0; q < 24; ++q) if (q == qq) v[q] = 3e38f;
      lmin = v[0]; larg = tid;
#pragma unroll
      for (int q = 1; q < 24; ++q) {
        int j = tid + (q << 8);
        if (v[q] < lmin) { lmin = v[q]; larg = j; }
      }
    }
    __syncthreads();
  }
}

// ------------------------------------------------- CSR build (deterministic)
__global__ __launch_bounds__(256) void offsets_kernel(
    const int* __restrict__ counts, int* __restrict__ offs, float* __restrict__ invd) {
  __shared__ int ssum[256];
  const int t = threadIdx.x;
  const int lo = t * 24;
  int hi = lo + 24; if (hi > NN) hi = NN;
  int s = 0;
  for (int i = lo; i < hi; ++i) s += counts[i];
  ssum[t] = s;
  __syncthreads();
  for (int o = 1; o < 256; o <<= 1) {
    int v2 = (t >= o) ? ssum[t - o] : 0;
    __syncthreads();
    ssum[t] += v2;
    __syncthreads();
  }
  int run = ssum[t] - s;
  for (int i = lo; i < hi; ++i) { offs[i] = run; run += counts[i]; }
  if (t == 255) offs[NN] = run;
  for (int i = t; i < NN; i += 256) {
    float c = (float)counts[i];
    invd[i] = 1.0f / fmaxf(c, 1.0f);
  }
}

__global__ __launch_bounds__(256) void scatter_kernel(
    const int* __restrict__ nbr, const int* __restrict__ offs,
    int* __restrict__ cursor, int* __restrict__ elist) {
  const int e = blockIdx.x * 256 + threadIdx.x;
  if (e >= EE) return;
  const int d = nbr[e];
  const int slot = offs[d] + atomicAdd(&cursor[d], 1);
  elist[slot] = e;
}

__global__ __launch_bounds__(256) void sortlists_kernel(
    const int* __restrict__ offs, int* __restrict__ elist) {
  const int b = blockIdx.x * 256 + threadIdx.x;
  if (b >= NN) return;
  const int s = offs[b], t = offs[b + 1];
  for (int i = s + 1; i < t; ++i) {
    int v = elist[i]; int j = i - 1;
    while (j >= s && elist[j] > v) { elist[j + 1] = elist[j]; --j; }
    elist[j + 1] = v;
  }
}

// --------------------------------------- weight transpose + bf16 conversion
// W: [LL][K][256] f32  ->  BT: [LL][256][Kpad] bf16 (zeros for k >= K)
__global__ __launch_bounds__(256) void wcvt_kernel(
    const float* __restrict__ W, unsigned short* __restrict__ BT,
    int K, int Kpad) {
  __shared__ unsigned short t[64][65];
  const int l = blockIdx.x, k0 = blockIdx.y * 64, n0 = blockIdx.z * 64;
  const int tid = threadIdx.x, tc = tid & 63, tr = tid >> 6;
  const float* Wl = W + (size_t)l * K * 256;
  unsigned short* BTl = BT + (size_t)l * 256 * Kpad;
  for (int r = tr; r < 64; r += 4) {
    int k = k0 + r;
    float v = (k < K) ? Wl[(size_t)k * 256 + n0 + tc] : 0.f;
    t[r][tc] = f2bf(v);
  }
  __syncthreads();
  for (int r = tr; r < 64; r += 4) {
    int n = n0 + r, k = k0 + tc;
    if (k < Kpad) BTl[(size_t)n * Kpad + k] = t[tc][r];
  }
}

// ---------------------------------------------------------------- encoder
__global__ __launch_bounds__(256) void enc_kernel(
    const float* __restrict__ pos, const float* __restrict__ W,
    const float* __restrict__ b, float* __restrict__ h,
    unsigned short* __restrict__ hb) {
  const int gidx = blockIdx.x * 256 + threadIdx.x;
  const int node = gidx >> 8, c = gidx & 255;
  float v = pos[node * 3 + 0] * W[c] + pos[node * 3 + 1] * W[HH + c] +
            pos[node * 3 + 2] * W[2 * HH + c] + b[c];
  h[gidx] = v;
  hb[gidx] = f2bf(v);
}

#define MFMA12 \
  acc[0][0] = __builtin_amdgcn_mfma_f32_16x16x32_bf16(ca0, cb0, acc[0][0], 0, 0, 0); \
  acc[0][1] = __builtin_amdgcn_mfma_f32_16x16x32_bf16(ca0, cb1, acc[0][1], 0, 0, 0); \
  acc[0][2] = __builtin_amdgcn_mfma_f32_16x16x32_bf16(ca0, cb2, acc[0][2], 0, 0, 0); \
  acc[0][3] = __builtin_amdgcn_mfma_f32_16x16x32_bf16(ca0, cb3, acc[0][3], 0, 0, 0); \
  acc[1][0] = __builtin_amdgcn_mfma_f32_16x16x32_bf16(ca1, cb0, acc[1][0], 0, 0, 0); \
  acc[1][1] = __builtin_amdgcn_mfma_f32_16x16x32_bf16(ca1, cb1, acc[1][1], 0, 0, 0); \
  acc[1][2] = __builtin_amdgcn_mfma_f32_16x16x32_bf16(ca1, cb2, acc[1][2], 0, 0, 0); \
  acc[1][3] = __builtin_amdgcn_mfma_f32_16x16x32_bf16(ca1, cb3, acc[1][3], 0, 0, 0); \
  acc[2][0] = __builtin_amdgcn_mfma_f32_16x16x32_bf16(ca2, cb0, acc[2][0], 0, 0, 0); \
  acc[2][1] = __builtin_amdgcn_mfma_f32_16x16x32_bf16(ca2, cb1, acc[2][1], 0, 0, 0); \
  acc[2][2] = __builtin_amdgcn_mfma_f32_16x16x32_bf16(ca2, cb2, acc[2][2], 0, 0, 0); \
  acc[2][3] = __builtin_amdgcn_mfma_f32_16x16x32_bf16(ca2, cb3, acc[2][3], 0, 0, 0);

// ------------------------------------------------------- msg (MFMA) + agg
__global__ __launch_bounds__(256, 2) void msg_mfma(
    const unsigned short* __restrict__ hb, float* __restrict__ agg,
    const int* __restrict__ elist, const int* __restrict__ nbr,
    const float* __restrict__ ea, const unsigned short* __restrict__ BT,
    const float* __restrict__ mb, const float* __restrict__ mg,
    const float* __restrict__ mbt) {
  __shared__ __align__(16) char smem[EB * RPAD * 2];  // feat (bf16) / mbuf (f32) overlay
  __shared__ int sdst[EB], ssrc[EB], seid[EB];
  __shared__ float psum[EB][4], psum2[EB][4], smu[EB], srs[EB];
  unsigned short* feat = (unsigned short*)smem;
  float* mbuf = (float*)smem;
  const int tid = threadIdx.x;
  const int base = blockIdx.x * EB;
  if (tid < EB) {
    int eid = elist[base + tid];
    seid[tid] = eid; sdst[tid] = nbr[eid]; ssrc[tid] = eid / KX;
  }
  __syncthreads();
  {
    const int lane = tid & 63, grp = tid >> 6;
    for (int it = 0; it < 24; ++it) {
      int hr = it * 4 + grp;
      int e = hr >> 1, half = hr & 1;
      int node = half ? ssrc[e] : sdst[e];
      ushort4 v = *(const ushort4*)(hb + (size_t)node * HH + (tid & 63) * 4);
      *(ushort4*)&feat[e * RPAD + half * HH + lane * 4] = v;
    }
  }
  for (int s = tid; s < EB * 4; s += 256) {
    int e = s >> 2, j = s & 3;
    feat[e * RPAD + 512 + j] = f2bf(ea[(size_t)seid[e] * 4 + j]);
  }
  for (int s = tid; s < EB * 28; s += 256) {
    int e = s / 28, k = s - e * 28;
    feat[e * RPAD + 516 + k] = 0;
  }
  __syncthreads();
  const int lane = tid & 63, wv = tid >> 6;
  const int m = lane & 15, g = lane >> 4;
  const int n0 = wv * 64;
  f32x4 acc[3][4] = {};
  {
    const unsigned short* a0p = feat + m * RPAD + g * 8;
    const unsigned short* a1p = a0p + 16 * RPAD;
    const unsigned short* a2p = a0p + 32 * RPAD;
    const unsigned short* bp0 = BT + (size_t)(n0 + m) * KPADM + g * 8;
    const unsigned short* bp1 = bp0 + 16 * KPADM;
    const unsigned short* bp2 = bp0 + 32 * KPADM;
    const unsigned short* bp3 = bp0 + 48 * KPADM;
    // 1-deep software pipeline: prefetch iter ks+1 before MFMAs of iter ks
    short8 cb0 = *(const short8*)(bp0);
    short8 cb1 = *(const short8*)(bp1);
    short8 cb2 = *(const short8*)(bp2);
    short8 cb3 = *(const short8*)(bp3);
    short8 ca0 = *(const short8*)(a0p);
    short8 ca1 = *(const short8*)(a1p);
    short8 ca2 = *(const short8*)(a2p);
    for (int ks = 0; ks < 16; ++ks) {
      const int ko = (ks + 1) * 32;
      short8 nb0 = *(const short8*)(bp0 + ko);
      short8 nb1 = *(const short8*)(bp1 + ko);
      short8 nb2 = *(const short8*)(bp2 + ko);
      short8 nb3 = *(const short8*)(bp3 + ko);
      short8 na0 = *(const short8*)(a0p + ko);
      short8 na1 = *(const short8*)(a1p + ko);
      short8 na2 = *(const short8*)(a2p + ko);
      MFMA12
      ca0 = na0; ca1 = na1; ca2 = na2;
      cb0 = nb0; cb1 = nb1; cb2 = nb2; cb3 = nb3;
    }
    MFMA12
  }
  float bb[4], gg4[4], be4[4];
#pragma unroll
  for (int nt = 0; nt < 4; ++nt) {
    int c = n0 + nt * 16 + m;
    bb[nt] = mb[c]; gg4[nt] = mg[c]; be4[nt] = mbt[c];
  }
#pragma unroll
  for (int rt = 0; rt < 3; ++rt)
#pragma unroll
    for (int i = 0; i < 4; ++i) {
      float s = 0.f, s2 = 0.f;
#pragma unroll
      for (int nt = 0; nt < 4; ++nt) {
        float v = fmaxf(acc[rt][nt][i] + bb[nt], 0.f);
        acc[rt][nt][i] = v; s += v; s2 += v * v;
      }
#pragma unroll
      for (int o = 1; o < 16; o <<= 1) {
        s += __shfl_xor(s, o, 64);
        s2 += __shfl_xor(s2, o, 64);
      }
      if (m == 0) { int e = rt * 16 + g * 4 + i; psum[e][wv] = s; psum2[e][wv] = s2; }
    }
  __syncthreads();
  if (tid < EB) {
    float s = psum[tid][0] + psum[tid][1] + psum[tid][2] + psum[tid][3];
    float s2 = psum2[tid][0] + psum2[tid][1] + psum2[tid][2] + psum2[tid][3];
    float mu = s * (1.f / HH);
    smu[tid] = mu;
    srs[tid] = rsqrtf(s2 * (1.f / HH) - mu * mu + 1e-5f);
  }
  __syncthreads();
  // write LN'd messages into mbuf (feat overlay; feat dead since MFMA loop)
#pragma unroll
  for (int rt = 0; rt < 3; ++rt)
#pragma unroll
    for (int i = 0; i < 4; ++i) {
      int e = rt * 16 + g * 4 + i;
      float mu = smu[e], rs = srs[e];
#pragma unroll
      for (int nt = 0; nt < 4; ++nt)
        mbuf[e * 260 + n0 + nt * 16 + m] = (acc[rt][nt][i] - mu) * rs * gg4[nt] + be4[nt];
    }
  __syncthreads();
  // dst-sorted run merge: one column per thread, ~2-4 atomics per column
  {
    float r = 0.f; int curd = sdst[0];
    for (int e = 0; e < EB; ++e) {
      int d = sdst[e];
      if (d != curd) {
        atomicAdd(&agg[(size_t)curd * HH + tid], r);
        r = 0.f; curd = d;
      }
      r += mbuf[e * 260 + tid];
    }
    atomicAdd(&agg[(size_t)curd * HH + tid], r);
  }
}

// ---------------------------------------------------------------- upd (MFMA)
__global__ __launch_bounds__(256, 2) void upd_mfma(
    float* __restrict__ h, unsigned short* __restrict__ hb,
    const float* __restrict__ agg, const float* __restrict__ invd,
    const unsigned short* __restrict__ BT, const float* __restrict__ ub,
    const float* __restrict__ ug, const float* __restrict__ ubt) {
  __shared__ __align__(16) unsigned short feat[UB * RPADU];
  __shared__ float psum[UB][4], psum2[UB][4], smu[UB], srs[UB], sinv[UB];
  const int tid = threadIdx.x;
  const int base = blockIdx.x * UB;
  if (tid < UB) sinv[tid] = invd[base + tid];
  __syncthreads();
  {
    const int lane = tid & 63, grp = tid >> 6;
    for (int it = 0; it < 8; ++it) {
      int hr = it * 4 + grp;
      int e = hr >> 1, half = hr & 1;
      int node = base + e;
      ushort4 o;
      if (half == 0) {
        o = *(const ushort4*)(hb + (size_t)node * HH + lane * 4);
      } else {
        float4 a4 = *(const float4*)(agg + (size_t)node * HH + lane * 4);
        float iv = sinv[e];
        o.x = f2bf(a4.x * iv); o.y = f2bf(a4.y * iv);
        o.z = f2bf(a4.z * iv); o.w = f2bf(a4.w * iv);
      }
      *(ushort4*)&feat[e * RPADU + half * HH + lane * 4] = o;
    }
  }
  __syncthreads();
  const int lane = tid & 63, wv = tid >> 6;
  const int m = lane & 15, g = lane >> 4;
  const int n0 = wv * 64;
  f32x4 acc[4] = {};
  {
    const unsigned short* ap = feat + m * RPADU + g * 8;
    const unsigned short* bp0 = BT + (size_t)(n0 + m) * KPADU + g * 8;
    const unsigned short* bp1 = bp0 + 16 * KPADU;
    const unsigned short* bp2 = bp0 + 32 * KPADU;
    const unsigned short* bp3 = bp0 + 48 * KPADU;
    short8 ca = *(const short8*)(ap);
    short8 cb0 = *(const short8*)(bp0);
    short8 cb1 = *(const short8*)(bp1);
    short8 cb2 = *(const short8*)(bp2);
    short8 cb3 = *(const short8*)(bp3);
    for (int ks = 0; ks < 15; ++ks) {
      const int ko = (ks + 1) * 32;
      short8 na = *(const short8*)(ap + ko);
      short8 nb0 = *(const short8*)(bp0 + ko);
      short8 nb1 = *(const short8*)(bp1 + ko);
      short8 nb2 = *(const short8*)(bp2 + ko);
      short8 nb3 = *(const short8*)(bp3 + ko);
      acc[0] = __builtin_amdgcn_mfma_f32_16x16x32_bf16(ca, cb0, acc[0], 0, 0, 0);
      acc[1] = __builtin_amdgcn_mfma_f32_16x16x32_bf16(ca, cb1, acc[1], 0, 0, 0);
      acc[2] = __builtin_amdgcn_mfma_f32_16x16x32_bf16(ca, cb2, acc[2], 0, 0, 0);
      acc[3] = __builtin_amdgcn_mfma_f32_16x16x32_bf16(ca, cb3, acc[3], 0, 0, 0);
      ca = na; cb0 = nb0; cb1 = nb1; cb2 = nb2; cb3 = nb3;
    }
    acc[0] = __builtin_amdgcn_mfma_f32_16x16x32_bf16(ca, cb0, acc[0], 0, 0, 0);
    acc[1] = __builtin_amdgcn_mfma_f32_16x16x32_bf16(ca, cb1, acc[1], 0, 0, 0);
    acc[2] = __builtin_amdgcn_mfma_f32_16x16x32_bf16(ca, cb2, acc[2], 0, 0, 0);
    acc[3] = __builtin_amdgcn_mfma_f32_16x16x32_bf16(ca, cb3, acc[3], 0, 0, 0);
  }
  float bb[4], gg4[4], be4[4];
#pragma unroll
  for (int nt = 0; nt < 4; ++nt) {
    int c = n0 + nt * 16 + m;
    bb[nt] = ub[c]; gg4[nt] = ug[c]; be4[nt] = ubt[c];
  }
#pragma unroll
  for (int i = 0; i < 4; ++i) {
    float s = 0.f, s2 = 0.f;
#pragma unroll
    for (int nt = 0; nt < 4; ++nt) {
      float v = fmaxf(acc[nt][i] + bb[nt], 0.f);
      acc[nt][i] = v; s += v; s2 += v * v;
    }
#pragma unroll
    for (int o = 1; o < 16; o <<= 1) {
      s += __shfl_xor(s, o, 64);
      s2 += __shfl_xor(s2, o, 64);
    }
    if (m == 0) { int e = g * 4 + i; psum[e][wv] = s; psum2[e][wv] = s2; }
  }
  __syncthreads();
  if (tid < UB) {
    float s = psum[tid][0] + psum[tid][1] + psum[tid][2] + psum[tid][3];
    float s2 = psum2[tid][0] + psum2[tid][1] + psum2[tid][2] + psum2[tid][3];
    float mu = s * (1.f / HH);
    smu[tid] = mu;
    srs[tid] = rsqrtf(s2 * (1.f / HH) - mu * mu + 1e-5f);
  }
  __syncthreads();
#pragma unroll
  for (int i = 0; i < 4; ++i) {
    int e = g * 4 + i;
    int node = base + e;
    float mu = smu[e], rs = srs[e];
#pragma unroll
    for (int nt = 0; nt < 4; ++nt) {
      int c = n0 + nt * 16 + m;
      float u = (acc[nt][i] - mu) * rs * gg4[nt] + be4[nt];
      float hn = h[(size_t)node * HH + c] + u;
      h[(size_t)node * HH + c] = hn;
      hb[(size_t)node * HH + c] = f2bf(hn);
    }
  }
}

// --------------------------------------------- fp32 register GEMM (proj only)
#define FMA4(J, F, W) { const float _f = (F); \
  acc[J][0] += _f * (W).x; acc[J][1] += _f * (W).y; \
  acc[J][2] += _f * (W).z; acc[J][3] += _f * (W).w; }

template <int ROWLEN, int KQ>
__device__ __forceinline__ void gemm16(const float* fbase, const float* wcol,
                                       float (&acc)[4][4], const int wv) {
  const float* f0p = fbase + (size_t)wv * ROWLEN;
  const float* f1p = f0p + 4 * ROWLEN;
  const float* f2p = f0p + 8 * ROWLEN;
  const float* f3p = f0p + 12 * ROWLEN;
  const float* wr = wcol;
#pragma unroll 2
  for (int kq = 0; kq < KQ; ++kq) {
    const int kk = kq * 4;
    const float4 w0 = *(const float4*)(wr + 0 * HH);
    const float4 w1 = *(const float4*)(wr + 1 * HH);
    const float4 w2 = *(const float4*)(wr + 2 * HH);
    const float4 w3 = *(const float4*)(wr + 3 * HH);
    const float4 f0 = *(const float4*)(f0p + kk);
    const float4 f1 = *(const float4*)(f1p + kk);
    const float4 f2 = *(const float4*)(f2p + kk);
    const float4 f3 = *(const float4*)(f3p + kk);
    FMA4(0, f0.x, w0) FMA4(0, f0.y, w1) FMA4(0, f0.z, w2) FMA4(0, f0.w, w3)
    FMA4(1, f1.x, w0) FMA4(1, f1.y, w1) FMA4(1, f1.z, w2) FMA4(1, f1.w, w3)
    FMA4(2, f2.x, w0) FMA4(2, f2.y, w1) FMA4(2, f2.z, w2) FMA4(2, f2.w, w3)
    FMA4(3, f3.x, w0) FMA4(3, f3.y, w1) FMA4(3, f3.z, w2) FMA4(3, f3.w, w3)
    wr += 4 * HH;
  }
}

// ---------------------------------------------------------------- projection
__global__ __launch_bounds__(256, 4) void proj_kernel(
    const float* __restrict__ h,
    const float* __restrict__ W1, const float* __restrict__ b1,
    const float* __restrict__ W2, const float* __restrict__ b2,
    float* __restrict__ out) {
  __shared__ float sh[16][256];
  __shared__ float st[16][256];
  const int tid = threadIdx.x, base = blockIdx.x * 16;
  for (int i = 0; i < 16; ++i) sh[i][tid] = h[(size_t)(base + i) * HH + tid];
  __syncthreads();
  const int lane = tid & 63, wv = tid >> 6;
  const int c4 = lane * 4;
  float acc[4][4] = {};
  gemm16<256, 64>(&sh[0][0], W1 + c4, acc, wv);
  const float4 bb = *(const float4*)(b1 + c4);
#pragma unroll
  for (int j = 0; j < 4; ++j) {
    const int e = wv + 4 * j;
    st[e][c4 + 0] = fmaxf(acc[j][0] + bb.x, 0.f);
    st[e][c4 + 1] = fmaxf(acc[j][1] + bb.y, 0.f);
    st[e][c4 + 2] = fmaxf(acc[j][2] + bb.z, 0.f);
    st[e][c4 + 3] = fmaxf(acc[j][3] + bb.w, 0.f);
  }
  __syncthreads();
  const int c2 = lane * 2;
  float a0[4] = {}, a1[4] = {};
  const float* w2p = W2 + c2;
#pragma unroll 2
  for (int kk = 0; kk < 256; ++kk) {
    const float2 w = *(const float2*)(w2p + (size_t)kk * PP);
    const float g0 = st[wv + 0][kk];
    const float g1 = st[wv + 4][kk];
    const float g2 = st[wv + 8][kk];
    const float g3 = st[wv + 12][kk];
    a0[0] += g0 * w.x; a1[0] += g0 * w.y;
    a0[1] += g1 * w.x; a1[1] += g1 * w.y;
    a0[2] += g2 * w.x; a1[2] += g2 * w.y;
    a0[3] += g3 * w.x; a1[3] += g3 * w.y;
  }
  const float2 b2v = *(const float2*)(b2 + c2);
#pragma unroll
  for (int j = 0; j < 4; ++j) {
    const int node = base + wv + 4 * j;
    out[(size_t)node * PP + c2 + 0] = a0[j] + b2v.x;
    out[(size_t)node * PP + c2 + 1] = a1[j] + b2v.y;
  }
}

// ---------------------------------------------------------------- launcher
extern "C" void kernel_launch(void* const* d_in, const int* in_sizes, int n_in,
                              void* d_out, int out_size, void* d_ws, size_t ws_size,
                              hipStream_t stream) {
  const float* pos   = (const float*)d_in[0];
  const float* box   = (const float*)d_in[1];
  const float* encW  = (const float*)d_in[2];
  const float* encB  = (const float*)d_in[3];
  const float* msgW  = (const float*)d_in[4];
  const float* msgB  = (const float*)d_in[5];
  const float* msgG  = (const float*)d_in[6];
  const float* msgBt = (const float*)d_in[7];
  const float* updW  = (const float*)d_in[8];
  const float* updB  = (const float*)d_in[9];
  const float* updG  = (const float*)d_in[10];
  const float* updBt = (const float*)d_in[11];
  const float* pW1   = (const float*)d_in[12];
  const float* pb1   = (const float*)d_in[13];
  const float* pW2   = (const float*)d_in[14];
  const float* pb2   = (const float*)d_in[15];
  float* out = (float*)d_out;

  char* w = (char*)d_ws;
  auto alloc = [&](size_t bytes) {
    char* p = w;
    w += (bytes + 255) & ~(size_t)255;
    return p;
  };
  int*   nbr    = (int*)alloc((size_t)EE * 4);
  float* ea     = (float*)alloc((size_t)EE * 16);
  int*   counts = (int*)alloc((size_t)NN * 4);
  int*   offs   = (int*)alloc((size_t)(NN + 1) * 4);
  int*   cursor = (int*)alloc((size_t)NN * 4);
  int*   elist  = (int*)alloc((size_t)EE * 4);
  float* invd   = (float*)alloc((size_t)NN * 4);
  float* hbuf   = (float*)alloc((size_t)NN * HH * 4);
  float* agg    = (float*)alloc((size_t)NN * HH * 4);
  unsigned short* hb  = (unsigned short*)alloc((size_t)NN * HH * 2);
  unsigned short* mBT = (unsigned short*)alloc((size_t)LL * 256 * KPADM * 2);
  unsigned short* uBT = (unsigned short*)alloc((size_t)LL * 256 * KPADU * 2);

  hipMemsetAsync(counts, 0, (size_t)NN * 4, stream);
  hipMemsetAsync(cursor, 0, (size_t)NN * 4, stream);

  wcvt_kernel<<<dim3(LL, 9, 4), 256, 0, stream>>>(msgW, mBT, 516, KPADM);
  wcvt_kernel<<<dim3(LL, 8, 4), 256, 0, stream>>>(updW, uBT, 512, KPADU);

  knn_kernel<<<NN, 256, 0, stream>>>(pos, box, nbr, ea, counts);
  offsets_kernel<<<1, 256, 0, stream>>>(counts, offs, invd);
  scatter_kernel<<<(EE + 255) / 256, 256, 0, stream>>>(nbr, offs, cursor, elist);
  sortlists_kernel<<<(NN + 255) / 256, 256, 0, stream>>>(offs, elist);
  enc_kernel<<<NN, 256, 0, stream>>>(pos, encW, encB, hbuf, hb);

  for (int l = 0; l < LL; ++l) {
    hipMemsetAsync(agg, 0, (size_t)NN * HH * 4, stream);
    msg_mfma<<<EE / EB, 256, 0, stream>>>(
        hb, agg, elist, nbr, ea,
        mBT + (size_t)l * 256 * KPADM,
        msgB + (size_t)l * HH, msgG + (size_t)l * HH, msgBt + (size_t)l * HH);
    upd_mfma<<<NN / UB, 256, 0, stream>>>(
        hbuf, hb, agg, invd,
        uBT + (size_t)l * 256 * KPADU,
        updB + (size_t)l * HH, updG + (size_t)l * HH, updBt + (size_t)l * HH);
  }
  proj_kernel<<<NN / 16, 256, 0, stream>>>(hbuf, pW1, pb1, pW2, pb2, out);
}

// Round 7
// 1310.504 us; speedup vs baseline: 7.0546x; 1.7847x over previous
//
#include <hip/hip_runtime.h>

#define NN 6000
#define HH 256
#define LL 10
#define KX 30
#define PP 128
#define EE (NN * KX)
#define KPADU 512    // upd BT row length
#define UB 16        // nodes per upd block
#define RPADU 520    // 1040B = 260 words == 4 mod 32 -> 2-way
#define RPQ 264      // pq A-tile row stride (ushorts)

typedef __attribute__((ext_vector_type(8))) short short8;
typedef __attribute__((ext_vector_type(4))) float f32x4;

__device__ __forceinline__ unsigned short f2bf(float x) {
  union { float f; unsigned u; } v; v.f = x;
  return (unsigned short)((v.u + 0x7fffu + ((v.u >> 16) & 1u)) >> 16);
}

// ---------------------------------------------------------------- kNN
__global__ __launch_bounds__(256) void knn_kernel(
    const float* __restrict__ pos, const float* __restrict__ box,
    int* __restrict__ nbr, float* __restrict__ ea, int* __restrict__ counts) {
  __shared__ float wvv[4];
  __shared__ int wvi[4];
  const int a = blockIdx.x, tid = threadIdx.x;
  const int lane = tid & 63, wv = tid >> 6;
  const float bx = box[0], by = box[1], bz = box[2];
  const float pax = pos[a * 3 + 0], pay = pos[a * 3 + 1], paz = pos[a * 3 + 2];
  float v[24];
#pragma unroll
  for (int q = 0; q < 24; ++q) {
    int j = tid + (q << 8);
    float d2 = 3e38f;
    if (j < NN && j != a) {
      float dx = pax - pos[j * 3 + 0]; dx -= rintf(dx / bx) * bx;
      float dy = pay - pos[j * 3 + 1]; dy -= rintf(dy / by) * by;
      float dz = paz - pos[j * 3 + 2]; dz -= rintf(dz / bz) * bz;
      d2 = dx * dx + dy * dy + dz * dz;
    }
    v[q] = d2;
  }
  float lmin = v[0]; int larg = tid;
#pragma unroll
  for (int q = 1; q < 24; ++q) {
    int j = tid + (q << 8);
    if (v[q] < lmin) { lmin = v[q]; larg = j; }
  }
  for (int r = 0; r < KX; ++r) {
    float m = lmin; int ar = larg;
#pragma unroll
    for (int o = 1; o < 64; o <<= 1) {
      float m2 = __shfl_xor(m, o, 64);
      int a2 = __shfl_xor(ar, o, 64);
      if (m2 < m || (m2 == m && a2 < ar)) { m = m2; ar = a2; }
    }
    if (lane == 0) { wvv[wv] = m; wvi[wv] = ar; }
    __syncthreads();
    float gm = wvv[0]; int ga = wvi[0];
#pragma unroll
    for (int w = 1; w < 4; ++w) {
      float m2 = wvv[w]; int a2 = wvi[w];
      if (m2 < gm || (m2 == gm && a2 < ga)) { gm = m2; ga = a2; }
    }
    if (tid == 0) {
      int b = ga;
      nbr[a * KX + r] = b;
      float dx = pax - pos[b * 3 + 0]; dx -= rintf(dx / bx) * bx;
      float dy = pay - pos[b * 3 + 1]; dy -= rintf(dy / by) * by;
      float dz = paz - pos[b * 3 + 2]; dz -= rintf(dz / bz) * bz;
      float4 e4; e4.x = dx; e4.y = dy; e4.z = dz; e4.w = sqrtf(gm);
      *(float4*)&ea[(a * KX + r) * 4] = e4;
      atomicAdd(&counts[b], 1);
    }
    if ((ga & 255) == tid) {
      const int qq = ga >> 8;
#pragma unroll
      for (int q = 0; q < 24; ++q) if (q == qq) v[q] = 3e38f;
      lmin = v[0]; larg = tid;
#pragma unroll
      for (int q = 1; q < 24; ++q) {
        int j = tid + (q << 8);
        if (v[q] < lmin) { lmin = v[q]; larg = j; }
      }
    }
    __syncthreads();
  }
}

// ------------------------------------------------- CSR build (deterministic)
__global__ __launch_bounds__(256) void offsets_kernel(
    const int* __restrict__ counts, int* __restrict__ offs, float* __restrict__ invd) {
  __shared__ int ssum[256];
  const int t = threadIdx.x;
  const int lo = t * 24;
  int hi = lo + 24; if (hi > NN) hi = NN;
  int s = 0;
  for (int i = lo; i < hi; ++i) s += counts[i];
  ssum[t] = s;
  __syncthreads();
  for (int o = 1; o < 256; o <<= 1) {
    int v2 = (t >= o) ? ssum[t - o] : 0;
    __syncthreads();
    ssum[t] += v2;
    __syncthreads();
  }
  int run = ssum[t] - s;
  for (int i = lo; i < hi; ++i) { offs[i] = run; run += counts[i]; }
  if (t == 255) offs[NN] = run;
  for (int i = t; i < NN; i += 256) {
    float c = (float)counts[i];
    invd[i] = 1.0f / fmaxf(c, 1.0f);
  }
}

__global__ __launch_bounds__(256) void scatter_kernel(
    const int* __restrict__ nbr, const int* __restrict__ offs,
    int* __restrict__ cursor, int* __restrict__ elist) {
  const int e = blockIdx.x * 256 + threadIdx.x;
  if (e >= EE) return;
  const int d = nbr[e];
  const int slot = offs[d] + atomicAdd(&cursor[d], 1);
  elist[slot] = e;
}

__global__ __launch_bounds__(256) void sortlists_kernel(
    const int* __restrict__ offs, int* __restrict__ elist) {
  const int b = blockIdx.x * 256 + threadIdx.x;
  if (b >= NN) return;
  const int s = offs[b], t = offs[b + 1];
  for (int i = s + 1; i < t; ++i) {
    int v = elist[i]; int j = i - 1;
    while (j >= s && elist[j] > v) { elist[j + 1] = elist[j]; --j; }
    elist[j + 1] = v;
  }
}

// --------------------------------------- weight transpose + bf16 conversion
// W rows [rowoff, rowoff+K) of a [*,256] f32 matrix -> BT[n][k] bf16 (row
// stride Kpad); per-layer strides lsW / lsBT.
__global__ __launch_bounds__(256) void wcvt_kernel(
    const float* __restrict__ W, unsigned short* __restrict__ BT,
    int K, int Kpad, int lsW, int lsBT, int rowoff) {
  __shared__ unsigned short t[64][65];
  const int l = blockIdx.x, k0 = blockIdx.y * 64, n0 = blockIdx.z * 64;
  const int tid = threadIdx.x, tc = tid & 63, tr = tid >> 6;
  const float* Wl = W + (size_t)l * lsW + (size_t)rowoff * 256;
  unsigned short* BTl = BT + (size_t)l * lsBT;
  for (int r = tr; r < 64; r += 4) {
    int k = k0 + r;
    float v = (k < K) ? Wl[(size_t)k * 256 + n0 + tc] : 0.f;
    t[r][tc] = f2bf(v);
  }
  __syncthreads();
  for (int r = tr; r < 64; r += 4) {
    int n = n0 + r, k = k0 + tc;
    if (k < Kpad) BTl[(size_t)n * Kpad + k] = t[tc][r];
  }
}

// ---------------------------------------------------------------- encoder
__global__ __launch_bounds__(256) void enc_kernel(
    const float* __restrict__ pos, const float* __restrict__ W,
    const float* __restrict__ b, float* __restrict__ h,
    unsigned short* __restrict__ hb) {
  const int gidx = blockIdx.x * 256 + threadIdx.x;
  const int node = gidx >> 8, c = gidx & 255;
  float v = pos[node * 3 + 0] * W[c] + pos[node * 3 + 1] * W[HH + c] +
            pos[node * 3 + 2] * W[2 * HH + c] + b[c];
  h[gidx] = v;
  hb[gidx] = f2bf(v);
}

// ------------------------------------------------- PQ = h @ [W_d | W_s] (+b on P)
// PQ[n][0:256] = h[n] @ W_d + msg_b ; PQ[n][256:512] = h[n] @ W_s. fp32 out.
__global__ __launch_bounds__(256, 2) void pq_mfma(
    const unsigned short* __restrict__ hb, float* __restrict__ PQ,
    const unsigned short* __restrict__ BT2, const float* __restrict__ mb) {
  __shared__ __align__(16) unsigned short A[16 * RPQ];
  const int tid = threadIdx.x;
  const int base = blockIdx.x * 16;
  const int lane = tid & 63, wv = tid >> 6;
  for (int it = 0; it < 4; ++it) {
    int row = it * 4 + wv;
    ushort4 v = *(const ushort4*)(hb + (size_t)(base + row) * HH + lane * 4);
    *(ushort4*)&A[row * RPQ + lane * 4] = v;
  }
  __syncthreads();
  const int m = lane & 15, g = lane >> 4;
  const int n0 = wv * 128;
  f32x4 acc[8] = {};
  const unsigned short* ap = A + m * RPQ + g * 8;
  const unsigned short* bp = BT2 + (size_t)(n0 + m) * 256 + g * 8;
  for (int ks = 0; ks < 8; ++ks) {
    const int ko = ks * 32;
    short8 a = *(const short8*)(ap + ko);
#pragma unroll
    for (int t = 0; t < 8; ++t)
      acc[t] = __builtin_amdgcn_mfma_f32_16x16x32_bf16(
          a, *(const short8*)(bp + (size_t)t * 16 * 256 + ko), acc[t], 0, 0, 0);
  }
#pragma unroll
  for (int t = 0; t < 8; ++t) {
    int c = n0 + t * 16 + m;
    float bias = (c < 256) ? mb[c] : 0.f;
#pragma unroll
    for (int i = 0; i < 4; ++i)
      PQ[(size_t)(base + g * 4 + i) * 512 + c] = acc[t][i] + bias;
  }
}

// ------------------------------------------------- edge pass: relu+LN+mean
// one 32-lane half-wave owns one dst's whole run: no atomics, no memset.
__global__ __launch_bounds__(256) void msg_edge(
    const float* __restrict__ PQ, float* __restrict__ agg,
    const int* __restrict__ elist, const int* __restrict__ offs,
    const float* __restrict__ invd, const float* __restrict__ ea,
    const float* __restrict__ msgWl, const float* __restrict__ mg,
    const float* __restrict__ mbt) {
  const int tid = threadIdx.x;
  const int h = tid & 31;
  const int d = blockIdx.x * 8 + (tid >> 5);
  const int c0 = h * 8;
  float we[4][8], gg[8], bt[8], p[8], acc[8];
#pragma unroll
  for (int j = 0; j < 4; ++j) {
    *(float4*)&we[j][0] = *(const float4*)(msgWl + (size_t)(512 + j) * 256 + c0);
    *(float4*)&we[j][4] = *(const float4*)(msgWl + (size_t)(512 + j) * 256 + c0 + 4);
  }
  *(float4*)&gg[0] = *(const float4*)(mg + c0);
  *(float4*)&gg[4] = *(const float4*)(mg + c0 + 4);
  *(float4*)&bt[0] = *(const float4*)(mbt + c0);
  *(float4*)&bt[4] = *(const float4*)(mbt + c0 + 4);
  *(float4*)&p[0] = *(const float4*)(PQ + (size_t)d * 512 + c0);
  *(float4*)&p[4] = *(const float4*)(PQ + (size_t)d * 512 + c0 + 4);
#pragma unroll
  for (int k = 0; k < 8; ++k) acc[k] = 0.f;
  const int s0 = offs[d], s1 = offs[d + 1];
  for (int e = s0; e < s1; ++e) {
    const int eid = elist[e];
    const int src = eid / KX;
    const float4 e4 = *(const float4*)(ea + (size_t)eid * 4);
    const float* qp = PQ + (size_t)src * 512 + 256 + c0;
    float q[8];
    *(float4*)&q[0] = *(const float4*)qp;
    *(float4*)&q[4] = *(const float4*)(qp + 4);
    float v[8], s = 0.f, s2 = 0.f;
#pragma unroll
    for (int k = 0; k < 8; ++k) {
      float z = p[k] + q[k] + e4.x * we[0][k] + e4.y * we[1][k] +
                e4.z * we[2][k] + e4.w * we[3][k];
      z = fmaxf(z, 0.f);
      v[k] = z; s += z; s2 += z * z;
    }
#pragma unroll
    for (int o = 1; o < 32; o <<= 1) {
      s += __shfl_xor(s, o, 64);
      s2 += __shfl_xor(s2, o, 64);
    }
    const float mu = s * (1.f / HH);
    const float rs = rsqrtf(s2 * (1.f / HH) - mu * mu + 1e-5f);
#pragma unroll
    for (int k = 0; k < 8; ++k) acc[k] += (v[k] - mu) * rs * gg[k] + bt[k];
  }
  const float iv = invd[d];
#pragma unroll
  for (int k = 0; k < 8; ++k) acc[k] *= iv;
  *(float4*)(agg + (size_t)d * 256 + c0) = *(float4*)&acc[0];
  *(float4*)(agg + (size_t)d * 256 + c0 + 4) = *(float4*)&acc[4];
}

// ---------------------------------------------------------------- upd (MFMA)
__global__ __launch_bounds__(256, 2) void upd_mfma(
    float* __restrict__ h, unsigned short* __restrict__ hb,
    const float* __restrict__ agg,
    const unsigned short* __restrict__ BT, const float* __restrict__ ub,
    const float* __restrict__ ug, const float* __restrict__ ubt) {
  __shared__ __align__(16) unsigned short feat[UB * RPADU];
  __shared__ float psum[UB][4], psum2[UB][4], smu[UB], srs[UB];
  const int tid = threadIdx.x;
  const int base = blockIdx.x * UB;
  {
    const int lane = tid & 63, grp = tid >> 6;
    for (int it = 0; it < 8; ++it) {
      int hr = it * 4 + grp;
      int e = hr >> 1, half = hr & 1;
      int node = base + e;
      ushort4 o;
      if (half == 0) {
        o = *(const ushort4*)(hb + (size_t)node * HH + lane * 4);
      } else {
        float4 a4 = *(const float4*)(agg + (size_t)node * HH + lane * 4);
        o.x = f2bf(a4.x); o.y = f2bf(a4.y);
        o.z = f2bf(a4.z); o.w = f2bf(a4.w);
      }
      *(ushort4*)&feat[e * RPADU + half * HH + lane * 4] = o;
    }
  }
  __syncthreads();
  const int lane = tid & 63, wv = tid >> 6;
  const int m = lane & 15, g = lane >> 4;
  const int n0 = wv * 64;
  f32x4 acc[4] = {};
  {
    const unsigned short* ap = feat + m * RPADU + g * 8;
    const unsigned short* bp0 = BT + (size_t)(n0 + m) * KPADU + g * 8;
    const unsigned short* bp1 = bp0 + 16 * KPADU;
    const unsigned short* bp2 = bp0 + 32 * KPADU;
    const unsigned short* bp3 = bp0 + 48 * KPADU;
    for (int ks = 0; ks < 16; ++ks) {
      const int ko = ks * 32;
      short8 a = *(const short8*)(ap + ko);
      acc[0] = __builtin_amdgcn_mfma_f32_16x16x32_bf16(a, *(const short8*)(bp0 + ko), acc[0], 0, 0, 0);
      acc[1] = __builtin_amdgcn_mfma_f32_16x16x32_bf16(a, *(const short8*)(bp1 + ko), acc[1], 0, 0, 0);
      acc[2] = __builtin_amdgcn_mfma_f32_16x16x32_bf16(a, *(const short8*)(bp2 + ko), acc[2], 0, 0, 0);
      acc[3] = __builtin_amdgcn_mfma_f32_16x16x32_bf16(a, *(const short8*)(bp3 + ko), acc[3], 0, 0, 0);
    }
  }
  float bb[4], gg4[4], be4[4];
#pragma unroll
  for (int nt = 0; nt < 4; ++nt) {
    int c = n0 + nt * 16 + m;
    bb[nt] = ub[c]; gg4[nt] = ug[c]; be4[nt] = ubt[c];
  }
#pragma unroll
  for (int i = 0; i < 4; ++i) {
    float s = 0.f, s2 = 0.f;
#pragma unroll
    for (int nt = 0; nt < 4; ++nt) {
      float v = fmaxf(acc[nt][i] + bb[nt], 0.f);
      acc[nt][i] = v; s += v; s2 += v * v;
    }
#pragma unroll
    for (int o = 1; o < 16; o <<= 1) {
      s += __shfl_xor(s, o, 64);
      s2 += __shfl_xor(s2, o, 64);
    }
    if (m == 0) { int e = g * 4 + i; psum[e][wv] = s; psum2[e][wv] = s2; }
  }
  __syncthreads();
  if (tid < UB) {
    float s = psum[tid][0] + psum[tid][1] + psum[tid][2] + psum[tid][3];
    float s2 = psum2[tid][0] + psum2[tid][1] + psum2[tid][2] + psum2[tid][3];
    float mu = s * (1.f / HH);
    smu[tid] = mu;
    srs[tid] = rsqrtf(s2 * (1.f / HH) - mu * mu + 1e-5f);
  }
  __syncthreads();
#pragma unroll
  for (int i = 0; i < 4; ++i) {
    int e = g * 4 + i;
    int node = base + e;
    float mu = smu[e], rs = srs[e];
#pragma unroll
    for (int nt = 0; nt < 4; ++nt) {
      int c = n0 + nt * 16 + m;
      float u = (acc[nt][i] - mu) * rs * gg4[nt] + be4[nt];
      float hn = h[(size_t)node * HH + c] + u;
      h[(size_t)node * HH + c] = hn;
      hb[(size_t)node * HH + c] = f2bf(hn);
    }
  }
}

// --------------------------------------------- fp32 register GEMM (proj only)
#define FMA4(J, F, W) { const float _f = (F); \
  acc[J][0] += _f * (W).x; acc[J][1] += _f * (W).y; \
  acc[J][2] += _f * (W).z; acc[J][3] += _f * (W).w; }

template <int ROWLEN, int KQ>
__device__ __forceinline__ void gemm16(const float* fbase, const float* wcol,
                                       float (&acc)[4][4], const int wv) {
  const float* f0p = fbase + (size_t)wv * ROWLEN;
  const float* f1p = f0p + 4 * ROWLEN;
  const float* f2p = f0p + 8 * ROWLEN;
  const float* f3p = f0p + 12 * ROWLEN;
  const float* wr = wcol;
#pragma unroll 2
  for (int kq = 0; kq < KQ; ++kq) {
    const int kk = kq * 4;
    const float4 w0 = *(const float4*)(wr + 0 * HH);
    const float4 w1 = *(const float4*)(wr + 1 * HH);
    const float4 w2 = *(const float4*)(wr + 2 * HH);
    const float4 w3 = *(const float4*)(wr + 3 * HH);
    const float4 f0 = *(const float4*)(f0p + kk);
    const float4 f1 = *(const float4*)(f1p + kk);
    const float4 f2 = *(const float4*)(f2p + kk);
    const float4 f3 = *(const float4*)(f3p + kk);
    FMA4(0, f0.x, w0) FMA4(0, f0.y, w1) FMA4(0, f0.z, w2) FMA4(0, f0.w, w3)
    FMA4(1, f1.x, w0) FMA4(1, f1.y, w1) FMA4(1, f1.z, w2) FMA4(1, f1.w, w3)
    FMA4(2, f2.x, w0) FMA4(2, f2.y, w1) FMA4(2, f2.z, w2) FMA4(2, f2.w, w3)
    FMA4(3, f3.x, w0) FMA4(3, f3.y, w1) FMA4(3, f3.z, w2) FMA4(3, f3.w, w3)
    wr += 4 * HH;
  }
}

// ---------------------------------------------------------------- projection
__global__ __launch_bounds__(256, 4) void proj_kernel(
    const float* __restrict__ h,
    const float* __restrict__ W1, const float* __restrict__ b1,
    const float* __restrict__ W2, const float* __restrict__ b2,
    float* __restrict__ out) {
  __shared__ float sh[16][256];
  __shared__ float st[16][256];
  const int tid = threadIdx.x, base = blockIdx.x * 16;
  for (int i = 0; i < 16; ++i) sh[i][tid] = h[(size_t)(base + i) * HH + tid];
  __syncthreads();
  const int lane = tid & 63, wv = tid >> 6;
  const int c4 = lane * 4;
  float acc[4][4] = {};
  gemm16<256, 64>(&sh[0][0], W1 + c4, acc, wv);
  const float4 bb = *(const float4*)(b1 + c4);
#pragma unroll
  for (int j = 0; j < 4; ++j) {
    const int e = wv + 4 * j;
    st[e][c4 + 0] = fmaxf(acc[j][0] + bb.x, 0.f);
    st[e][c4 + 1] = fmaxf(acc[j][1] + bb.y, 0.f);
    st[e][c4 + 2] = fmaxf(acc[j][2] + bb.z, 0.f);
    st[e][c4 + 3] = fmaxf(acc[j][3] + bb.w, 0.f);
  }
  __syncthreads();
  const int c2 = lane * 2;
  float a0[4] = {}, a1[4] = {};
  const float* w2p = W2 + c2;
#pragma unroll 2
  for (int kk = 0; kk < 256; ++kk) {
    const float2 w = *(const float2*)(w2p + (size_t)kk * PP);
    const float g0 = st[wv + 0][kk];
    const float g1 = st[wv + 4][kk];
    const float g2 = st[wv + 8][kk];
    const float g3 = st[wv + 12][kk];
    a0[0] += g0 * w.x; a1[0] += g0 * w.y;
    a0[1] += g1 * w.x; a1[1] += g1 * w.y;
    a0[2] += g2 * w.x; a1[2] += g2 * w.y;
    a0[3] += g3 * w.x; a1[3] += g3 * w.y;
  }
  const float2 b2v = *(const float2*)(b2 + c2);
#pragma unroll
  for (int j = 0; j < 4; ++j) {
    const int node = base + wv + 4 * j;
    out[(size_t)node * PP + c2 + 0] = a0[j] + b2v.x;
    out[(size_t)node * PP + c2 + 1] = a1[j] + b2v.y;
  }
}

// ---------------------------------------------------------------- launcher
extern "C" void kernel_launch(void* const* d_in, const int* in_sizes, int n_in,
                              void* d_out, int out_size, void* d_ws, size_t ws_size,
                              hipStream_t stream) {
  const float* pos   = (const float*)d_in[0];
  const float* box   = (const float*)d_in[1];
  const float* encW  = (const float*)d_in[2];
  const float* encB  = (const float*)d_in[3];
  const float* msgW  = (const float*)d_in[4];
  const float* msgB  = (const float*)d_in[5];
  const float* msgG  = (const float*)d_in[6];
  const float* msgBt = (const float*)d_in[7];
  const float* updW  = (const float*)d_in[8];
  const float* updB  = (const float*)d_in[9];
  const float* updG  = (const float*)d_in[10];
  const float* updBt = (const float*)d_in[11];
  const float* pW1   = (const float*)d_in[12];
  const float* pb1   = (const float*)d_in[13];
  const float* pW2   = (const float*)d_in[14];
  const float* pb2   = (const float*)d_in[15];
  float* out = (float*)d_out;

  char* w = (char*)d_ws;
  auto alloc = [&](size_t bytes) {
    char* p = w;
    w += (bytes + 255) & ~(size_t)255;
    return p;
  };
  int*   nbr    = (int*)alloc((size_t)EE * 4);
  float* ea     = (float*)alloc((size_t)EE * 16);
  int*   counts = (int*)alloc((size_t)NN * 4);
  int*   offs   = (int*)alloc((size_t)(NN + 1) * 4);
  int*   cursor = (int*)alloc((size_t)NN * 4);
  int*   elist  = (int*)alloc((size_t)EE * 4);
  float* invd   = (float*)alloc((size_t)NN * 4);
  float* hbuf   = (float*)alloc((size_t)NN * HH * 4);
  float* agg    = (float*)alloc((size_t)NN * HH * 4);
  float* PQ     = (float*)alloc((size_t)NN * 512 * 4);
  unsigned short* hb   = (unsigned short*)alloc((size_t)NN * HH * 2);
  unsigned short* mBT2 = (unsigned short*)alloc((size_t)LL * 512 * 256 * 2);
  unsigned short* uBT  = (unsigned short*)alloc((size_t)LL * 256 * KPADU * 2);

  hipMemsetAsync(counts, 0, (size_t)NN * 4, stream);
  hipMemsetAsync(cursor, 0, (size_t)NN * 4, stream);

  // BT2 rows 0..255 = W_d^T (msgW rows 0..255); rows 256..511 = W_s^T
  wcvt_kernel<<<dim3(LL, 4, 4), 256, 0, stream>>>(
      msgW, mBT2, 256, 256, 516 * 256, 512 * 256, 0);
  wcvt_kernel<<<dim3(LL, 4, 4), 256, 0, stream>>>(
      msgW, mBT2 + 256 * 256, 256, 256, 516 * 256, 512 * 256, 256);
  wcvt_kernel<<<dim3(LL, 8, 4), 256, 0, stream>>>(
      updW, uBT, 512, 512, 512 * 256, 256 * 512, 0);

  knn_kernel<<<NN, 256, 0, stream>>>(pos, box, nbr, ea, counts);
  offsets_kernel<<<1, 256, 0, stream>>>(counts, offs, invd);
  scatter_kernel<<<(EE + 255) / 256, 256, 0, stream>>>(nbr, offs, cursor, elist);
  sortlists_kernel<<<(NN + 255) / 256, 256, 0, stream>>>(offs, elist);
  enc_kernel<<<NN, 256, 0, stream>>>(pos, encW, encB, hbuf, hb);

  for (int l = 0; l < LL; ++l) {
    pq_mfma<<<NN / 16, 256, 0, stream>>>(
        hb, PQ, mBT2 + (size_t)l * 512 * 256, msgB + (size_t)l * HH);
    msg_edge<<<NN / 8, 256, 0, stream>>>(
        PQ, agg, elist, offs, invd, ea,
        msgW + (size_t)l * 516 * 256,
        msgG + (size_t)l * HH, msgBt + (size_t)l * HH);
    upd_mfma<<<NN / UB, 256, 0, stream>>>(
        hbuf, hb, agg,
        uBT + (size_t)l * 256 * KPADU,
        updB + (size_t)l * HH, updG + (size_t)l * HH, updBt + (size_t)l * HH);
  }
  proj_kernel<<<NN / 16, 256, 0, stream>>>(hbuf, pW1, pb1, pW2, pb2, out);
}